// Round 1
// baseline (961.569 us; speedup 1.0000x reference)
//
#include <hip/hip_runtime.h>
#include <math.h>

#define B_  2
#define S_  2048
#define D_  1024
#define H_  16
#define HD_ 64
#define M_  (B_*S_)      // 4096 rows in the GEMMs
#define CH_ 32           // scan chunks per sequence
#define CL_ 64           // scan chunk length (CH_*CL_ == S_)

// ---------------------------------------------------------------------------
// GEMM: C[m,n] = act( sum_k A[m,k] * W[k,n] + bias[n] )   (ACT 0=none 1=sigmoid)
// 64x64 block tile, BK=16, 256 threads, 4x4 micro-tile per thread.
// ---------------------------------------------------------------------------
template <int ACT>
__global__ __launch_bounds__(256)
void gemm_kernel(const float* __restrict__ A, const float* __restrict__ W,
                 const float* __restrict__ bias, float* __restrict__ C) {
    const int K = D_, N = D_;
    __shared__ float As[16][68];   // [k][m] (transposed, +4 pad keeps 16B align)
    __shared__ float Bs[16][68];   // [k][n]
    const int tid = threadIdx.x;
    const int n0 = blockIdx.x * 64;
    const int m0 = blockIdx.y * 64;
    const int tm = tid >> 4, tn = tid & 15;
    // loader indices
    const int lr = tid >> 2;            // A-tile row 0..63
    const int lc = (tid & 3) * 4;       // A-tile col4 0..12
    const int wr = tid >> 4;            // W-tile row 0..15
    const int wc = (tid & 15) * 4;      // W-tile col4

    float acc[4][4] = {};

    for (int k0 = 0; k0 < K; k0 += 16) {
        float4 a4 = *(const float4*)(A + (size_t)(m0 + lr) * K + k0 + lc);
        float4 w4 = *(const float4*)(W + (size_t)(k0 + wr) * N + n0 + wc);
        __syncthreads();   // protect previous iteration's LDS reads
        As[lc + 0][lr] = a4.x; As[lc + 1][lr] = a4.y;
        As[lc + 2][lr] = a4.z; As[lc + 3][lr] = a4.w;
        *(float4*)&Bs[wr][wc] = w4;
        __syncthreads();
        #pragma unroll
        for (int k = 0; k < 16; ++k) {
            float4 av = *(const float4*)&As[k][tm * 4];
            float4 bv = *(const float4*)&Bs[k][tn * 4];
            float ar[4] = {av.x, av.y, av.z, av.w};
            float br[4] = {bv.x, bv.y, bv.z, bv.w};
            #pragma unroll
            for (int i = 0; i < 4; ++i)
                #pragma unroll
                for (int j = 0; j < 4; ++j)
                    acc[i][j] = fmaf(ar[i], br[j], acc[i][j]);
        }
    }

    float4 bv = *(const float4*)(bias + n0 + tn * 4);
    float bb[4] = {bv.x, bv.y, bv.z, bv.w};
    #pragma unroll
    for (int i = 0; i < 4; ++i) {
        const int m = m0 + tm * 4 + i;
        float o[4];
        #pragma unroll
        for (int j = 0; j < 4; ++j) {
            float x = acc[i][j] + bb[j];
            if (ACT == 1) x = 1.0f / (1.0f + expf(-x));
            o[j] = x;
        }
        *(float4*)(C + (size_t)m * N + n0 + tn * 4) = make_float4(o[0], o[1], o[2], o[3]);
    }
}

// ---------------------------------------------------------------------------
// Chunked gated scan: h_t = a_t * h_{t-1} + u_t over S, per (b,d) channel.
// ---------------------------------------------------------------------------
__global__ __launch_bounds__(256)
void scan_pass1(const float* __restrict__ a, const float* __restrict__ u,
                float* __restrict__ cA, float* __restrict__ cU) {
    const int tid = blockIdx.x * blockDim.x + threadIdx.x;   // b*CH*D + c*D + d
    const int d = tid % D_;
    const int c = (tid / D_) % CH_;
    const int b = tid / (D_ * CH_);
    size_t base = ((size_t)b * S_ + (size_t)c * CL_) * D_ + d;
    float A = 1.0f, h = 0.0f;
    for (int i = 0; i < CL_; ++i) {
        float av = a[base + (size_t)i * D_];
        float uv = u[base + (size_t)i * D_];
        A *= av;
        h = fmaf(av, h, uv);
    }
    cA[tid] = A;
    cU[tid] = h;
}

__global__ __launch_bounds__(256)
void scan_pass2(const float* __restrict__ cA, const float* __restrict__ cU,
                float* __restrict__ cIn) {
    const int tid = blockIdx.x * blockDim.x + threadIdx.x;   // b*D + d
    const int d = tid % D_;
    const int b = tid / D_;
    float h = 0.0f;
    for (int c = 0; c < CH_; ++c) {
        const int idx = (b * CH_ + c) * D_ + d;
        float A = cA[idx], U = cU[idx];
        cIn[idx] = h;                // carry-in for chunk c
        h = fmaf(A, h, U);
    }
}

__global__ __launch_bounds__(256)
void scan_pass3(const float* __restrict__ a, const float* __restrict__ u,
                const float* __restrict__ cIn, float* __restrict__ hout) {
    const int tid = blockIdx.x * blockDim.x + threadIdx.x;
    const int d = tid % D_;
    const int c = (tid / D_) % CH_;
    const int b = tid / (D_ * CH_);
    size_t base = ((size_t)b * S_ + (size_t)c * CL_) * D_ + d;
    float h = cIn[tid];
    for (int i = 0; i < CL_; ++i) {
        float av = a[base + (size_t)i * D_];
        float uv = u[base + (size_t)i * D_];
        h = fmaf(av, h, uv);
        hout[base + (size_t)i * D_] = h;
    }
}

// ---------------------------------------------------------------------------
// Retention: out[b,n,h*64+hd] = sum_{m<=n} gamma_h^(n-m) * (q.k/8) * v[m,hd]
// One block per (n-tile=64, head, batch). Flash-style over causal m-tiles.
// ---------------------------------------------------------------------------
__global__ __launch_bounds__(256)
void retention_kernel(const float* __restrict__ Q, const float* __restrict__ Kk,
                      const float* __restrict__ V, const float* __restrict__ gammas,
                      float* __restrict__ Out) {
    __shared__ float Qt[64][68];   // [d][n]
    __shared__ float Kt[64][68];   // [d][m]
    __shared__ float Vs[64][68];   // [m][hd]
    __shared__ float St[64][68];   // [m][n]  weighted scores
    const int tid = threadIdx.x;
    const int nt = blockIdx.x;
    const int h  = blockIdx.y;
    const int b  = blockIdx.z;
    const int n0 = nt * 64;
    const float lg = log2f(gammas[h]);
    const int tm = tid >> 4, tn = tid & 15;
    const int lr0 = tid >> 4;          // 0..15, +j*16 for 4 rows
    const int lc4 = (tid & 15) * 4;    // 0..60

    // load Q tile transposed: Qt[d][n]
    #pragma unroll
    for (int j = 0; j < 4; ++j) {
        const int r = lr0 + j * 16;
        float4 q4 = *(const float4*)(Q + ((size_t)(b * S_ + n0 + r)) * D_ + h * HD_ + lc4);
        Qt[lc4 + 0][r] = q4.x; Qt[lc4 + 1][r] = q4.y;
        Qt[lc4 + 2][r] = q4.z; Qt[lc4 + 3][r] = q4.w;
    }

    float o[4][4] = {};

    for (int mt = 0; mt <= nt; ++mt) {
        const int m0 = mt * 64;
        __syncthreads();   // protect Qt (iter 0) and Kt/Vs/St from previous iter
        #pragma unroll
        for (int j = 0; j < 4; ++j) {
            const int r = lr0 + j * 16;
            float4 k4 = *(const float4*)(Kk + ((size_t)(b * S_ + m0 + r)) * D_ + h * HD_ + lc4);
            Kt[lc4 + 0][r] = k4.x; Kt[lc4 + 1][r] = k4.y;
            Kt[lc4 + 2][r] = k4.z; Kt[lc4 + 3][r] = k4.w;
            float4 v4 = *(const float4*)(V + ((size_t)(b * S_ + m0 + r)) * D_ + h * HD_ + lc4);
            *(float4*)&Vs[r][lc4] = v4;
        }
        __syncthreads();

        // s[n,m] = Q . K
        float s[4][4] = {};
        #pragma unroll 8
        for (int d = 0; d < 64; ++d) {
            float4 qv = *(const float4*)&Qt[d][tm * 4];
            float4 kv = *(const float4*)&Kt[d][tn * 4];
            float qr[4] = {qv.x, qv.y, qv.z, qv.w};
            float kr[4] = {kv.x, kv.y, kv.z, kv.w};
            #pragma unroll
            for (int i = 0; i < 4; ++i)
                #pragma unroll
                for (int j = 0; j < 4; ++j)
                    s[i][j] = fmaf(qr[i], kr[j], s[i][j]);
        }
        // apply decay weight + 1/sqrt(HD), write St[m][n]
        #pragma unroll
        for (int j = 0; j < 4; ++j) {
            float col[4];
            #pragma unroll
            for (int i = 0; i < 4; ++i) {
                const int n = n0 + tm * 4 + i;
                const int m = m0 + tn * 4 + j;
                const int delta = n - m;
                float w = (delta >= 0) ? exp2f((float)delta * lg) * 0.125f : 0.0f;
                col[i] = s[i][j] * w;
            }
            *(float4*)&St[tn * 4 + j][tm * 4] = make_float4(col[0], col[1], col[2], col[3]);
        }
        __syncthreads();

        // O[n,hd] += sum_m St[m][n] * Vs[m][hd]
        #pragma unroll 8
        for (int m = 0; m < 64; ++m) {
            float4 av = *(const float4*)&St[m][tm * 4];
            float4 vv = *(const float4*)&Vs[m][tn * 4];
            float ar[4] = {av.x, av.y, av.z, av.w};
            float vr[4] = {vv.x, vv.y, vv.z, vv.w};
            #pragma unroll
            for (int i = 0; i < 4; ++i)
                #pragma unroll
                for (int j = 0; j < 4; ++j)
                    o[i][j] = fmaf(ar[i], vr[j], o[i][j]);
        }
    }

    #pragma unroll
    for (int i = 0; i < 4; ++i) {
        const int n = n0 + tm * 4 + i;
        *(float4*)(Out + ((size_t)(b * S_ + n)) * D_ + h * HD_ + tn * 4) =
            make_float4(o[i][0], o[i][1], o[i][2], o[i][3]);
    }
}

// ---------------------------------------------------------------------------
extern "C" void kernel_launch(void* const* d_in, const int* in_sizes, int n_in,
                              void* d_out, int out_size, void* d_ws, size_t ws_size,
                              hipStream_t stream) {
    const float* q      = (const float*)d_in[0];
    const float* k      = (const float*)d_in[1];
    const float* v      = (const float*)d_in[2];
    const float* W_in   = (const float*)d_in[3];
    const float* b_in   = (const float*)d_in[4];
    const float* W_gate = (const float*)d_in[5];
    const float* b_gate = (const float*)d_in[6];
    const float* W_out  = (const float*)d_in[7];
    const float* b_out  = (const float*)d_in[8];
    const float* gammas = (const float*)d_in[9];
    float* out = (float*)d_out;

    float* ws = (float*)d_ws;
    const size_t MD = (size_t)M_ * D_;              // 4M floats
    float* u_buf = ws;                              // [M,D]
    float* a_buf = ws + MD;                         // [M,D]
    float* h_buf = ws + 2 * MD;                     // [M,D]
    float* cA    = ws + 3 * MD;                     // [B,CH,D]
    float* cU    = cA + (size_t)B_ * CH_ * D_;
    float* cIn   = cU + (size_t)B_ * CH_ * D_;
    float* qproj = u_buf;                           // reuse after scan

    dim3 ggrid(D_ / 64, M_ / 64);
    gemm_kernel<0><<<ggrid, 256, 0, stream>>>(q, W_in, b_in, u_buf);
    gemm_kernel<1><<<ggrid, 256, 0, stream>>>(q, W_gate, b_gate, a_buf);

    scan_pass1<<<(B_ * CH_ * D_) / 256, 256, 0, stream>>>(a_buf, u_buf, cA, cU);
    scan_pass2<<<(B_ * D_) / 256, 256, 0, stream>>>(cA, cU, cIn);
    scan_pass3<<<(B_ * CH_ * D_) / 256, 256, 0, stream>>>(a_buf, u_buf, cIn, h_buf);

    gemm_kernel<0><<<ggrid, 256, 0, stream>>>(h_buf, W_out, b_out, qproj);

    retention_kernel<<<dim3(S_ / 64, H_, B_), 256, 0, stream>>>(qproj, k, v, gammas, out);
}

// Round 3
// 323.649 us; speedup vs baseline: 2.9710x; 2.9710x over previous
//
#include <hip/hip_runtime.h>
#include <math.h>

#define B_  2
#define S_  2048
#define D_  1024
#define H_  16
#define HD_ 64
#define M_  (B_*S_)      // 4096 rows in the GEMMs
#define CH_ 32           // scan chunks per sequence
#define CL_ 64           // scan chunk length (CH_*CL_ == S_)

typedef unsigned short ushort_t;
typedef unsigned int   uint_t;
typedef __attribute__((ext_vector_type(8))) short bf16x8;
typedef __attribute__((ext_vector_type(4))) float f32x4;

__device__ __forceinline__ ushort_t f2bf(float f) {
    uint_t u = __builtin_bit_cast(uint_t, f);
    u += 0x7FFFu + ((u >> 16) & 1u);           // RNE
    return (ushort_t)(u >> 16);
}
__device__ __forceinline__ float bf2f(ushort_t h) {
    uint_t u = (uint_t)h << 16;
    return __builtin_bit_cast(float, u);
}
__device__ __forceinline__ uint_t pk2(float x, float y) {
    return (uint_t)f2bf(x) | ((uint_t)f2bf(y) << 16);
}

// ---------------------------------------------------------------------------
// Transpose + convert: W [K=1024][N=1024] f32 -> WT [N][K] bf16
// ---------------------------------------------------------------------------
__global__ __launch_bounds__(256)
void transp_cvt(const float* __restrict__ W, ushort_t* __restrict__ WT) {
    __shared__ float T[32][36];
    const int kt = blockIdx.x, nt = blockIdx.y;
    const int t = threadIdx.x;
    const int rr = t >> 3, cc = (t & 7) * 4;
    float4 w4 = *(const float4*)(W + (size_t)(kt * 32 + rr) * D_ + nt * 32 + cc);
    T[rr][cc + 0] = w4.x; T[rr][cc + 1] = w4.y; T[rr][cc + 2] = w4.z; T[rr][cc + 3] = w4.w;
    __syncthreads();
    ushort_t o[4];
    #pragma unroll
    for (int j = 0; j < 4; ++j) o[j] = f2bf(T[cc + j][rr]);
    *(ushort4*)(WT + (size_t)(nt * 32 + rr) * D_ + kt * 32 + cc) =
        make_ushort4(o[0], o[1], o[2], o[3]);
}

// ---------------------------------------------------------------------------
// Elementwise convert f32 -> bf16 (for q)
// ---------------------------------------------------------------------------
__global__ __launch_bounds__(256)
void cvt_bf16(const float* __restrict__ X, ushort_t* __restrict__ Y) {
    const int i = (blockIdx.x * 256 + threadIdx.x) * 4;
    float4 x = *(const float4*)(X + i);
    *(ushort4*)(Y + i) = make_ushort4(f2bf(x.x), f2bf(x.y), f2bf(x.z), f2bf(x.w));
}

// ---------------------------------------------------------------------------
// bf16 MFMA GEMM: C[m,n] = act( A[m,:] . WT[n,:] + bias[n] )
// A [M][1024] bf16, WT [1024][1024] bf16 (n-major). 128x128 tile, BK=64.
// ACT: 0 none, 1 sigmoid.  OUTBF: write bf16 (Cb) else f32 (Cf).
// ---------------------------------------------------------------------------
template <int ACT, int OUTBF>
__global__ __launch_bounds__(256)
void gemm_mfma(const ushort_t* __restrict__ A, const ushort_t* __restrict__ BT,
               const float* __restrict__ bias, float* __restrict__ Cf,
               ushort_t* __restrict__ Cb) {
    const int K = D_, N = D_;
    __shared__ ushort_t As[128 * 72];   // rows m, cols k, stride 72 (pad 8)
    __shared__ ushort_t Bs[128 * 72];   // rows n, cols k
    const int tid = threadIdx.x;
    const int n0 = blockIdx.x * 128, m0 = blockIdx.y * 128;
    const int w = tid >> 6, lane = tid & 63, quad = lane >> 4, l15 = lane & 15;
    const int wr = (w >> 1) * 64, wc = (w & 1) * 64;
    const int sr = tid >> 1, sh = (tid & 1) * 32;   // staging: row, 32-col half

    f32x4 acc[4][4] = {};
    const ushort_t* Ag = A  + (size_t)(m0 + sr) * K + sh;
    const ushort_t* Bg = BT + (size_t)(n0 + sr) * K + sh;

    for (int k0 = 0; k0 < K; k0 += 64) {
        // 32 ushorts (64 B) per thread per operand = 4 x uint4 (8 ushorts each)
        uint4 a0 = *(const uint4*)(Ag + k0 +  0);
        uint4 a1 = *(const uint4*)(Ag + k0 +  8);
        uint4 a2 = *(const uint4*)(Ag + k0 + 16);
        uint4 a3 = *(const uint4*)(Ag + k0 + 24);
        uint4 b0 = *(const uint4*)(Bg + k0 +  0);
        uint4 b1 = *(const uint4*)(Bg + k0 +  8);
        uint4 b2 = *(const uint4*)(Bg + k0 + 16);
        uint4 b3 = *(const uint4*)(Bg + k0 + 24);
        __syncthreads();
        *(uint4*)&As[sr * 72 + sh +  0] = a0;
        *(uint4*)&As[sr * 72 + sh +  8] = a1;
        *(uint4*)&As[sr * 72 + sh + 16] = a2;
        *(uint4*)&As[sr * 72 + sh + 24] = a3;
        *(uint4*)&Bs[sr * 72 + sh +  0] = b0;
        *(uint4*)&Bs[sr * 72 + sh +  8] = b1;
        *(uint4*)&Bs[sr * 72 + sh + 16] = b2;
        *(uint4*)&Bs[sr * 72 + sh + 24] = b3;
        __syncthreads();
        #pragma unroll
        for (int kk = 0; kk < 2; ++kk) {
            bf16x8 af[4], bf[4];
            #pragma unroll
            for (int i = 0; i < 4; ++i)
                af[i] = *(const bf16x8*)&As[(wr + 16 * i + l15) * 72 + kk * 32 + quad * 8];
            #pragma unroll
            for (int j = 0; j < 4; ++j)
                bf[j] = *(const bf16x8*)&Bs[(wc + 16 * j + l15) * 72 + kk * 32 + quad * 8];
            #pragma unroll
            for (int i = 0; i < 4; ++i)
                #pragma unroll
                for (int j = 0; j < 4; ++j)
                    acc[i][j] = __builtin_amdgcn_mfma_f32_16x16x32_bf16(
                        af[i], bf[j], acc[i][j], 0, 0, 0);
        }
    }

    #pragma unroll
    for (int j = 0; j < 4; ++j) {
        const int n = n0 + wc + 16 * j + l15;
        const float bb = bias[n];
        #pragma unroll
        for (int i = 0; i < 4; ++i) {
            #pragma unroll
            for (int r = 0; r < 4; ++r) {
                const int m = m0 + wr + 16 * i + quad * 4 + r;
                float x = acc[i][j][r] + bb;
                if (ACT == 1) x = 1.0f / (1.0f + __expf(-x));
                if (OUTBF) Cb[(size_t)m * N + n] = f2bf(x);
                else       Cf[(size_t)m * N + n] = x;
            }
        }
    }
}

// ---------------------------------------------------------------------------
// Chunked gated scan: h_t = a_t * h_{t-1} + u_t.  a f32, u bf16, h out bf16.
// ---------------------------------------------------------------------------
__global__ __launch_bounds__(256)
void scan_pass1(const float* __restrict__ a, const ushort_t* __restrict__ u,
                float* __restrict__ cA, float* __restrict__ cU) {
    const int tid = blockIdx.x * blockDim.x + threadIdx.x;
    const int d = tid % D_;
    const int c = (tid / D_) % CH_;
    const int b = tid / (D_ * CH_);
    size_t base = ((size_t)b * S_ + (size_t)c * CL_) * D_ + d;
    float A = 1.0f, h = 0.0f;
    for (int i = 0; i < CL_; ++i) {
        float av = a[base + (size_t)i * D_];
        float uv = bf2f(u[base + (size_t)i * D_]);
        A *= av;
        h = fmaf(av, h, uv);
    }
    cA[tid] = A;
    cU[tid] = h;
}

__global__ __launch_bounds__(256)
void scan_pass2(const float* __restrict__ cA, const float* __restrict__ cU,
                float* __restrict__ cIn) {
    const int tid = blockIdx.x * blockDim.x + threadIdx.x;
    const int d = tid % D_;
    const int b = tid / D_;
    float h = 0.0f;
    for (int c = 0; c < CH_; ++c) {
        const int idx = (b * CH_ + c) * D_ + d;
        float A = cA[idx], U = cU[idx];
        cIn[idx] = h;
        h = fmaf(A, h, U);
    }
}

__global__ __launch_bounds__(256)
void scan_pass3(const float* __restrict__ a, const ushort_t* __restrict__ u,
                const float* __restrict__ cIn, ushort_t* __restrict__ hout) {
    const int tid = blockIdx.x * blockDim.x + threadIdx.x;
    const int d = tid % D_;
    const int c = (tid / D_) % CH_;
    const int b = tid / (D_ * CH_);
    size_t base = ((size_t)b * S_ + (size_t)c * CL_) * D_ + d;
    float h = cIn[tid];
    for (int i = 0; i < CL_; ++i) {
        float av = a[base + (size_t)i * D_];
        float uv = bf2f(u[base + (size_t)i * D_]);
        h = fmaf(av, h, uv);
        hout[base + (size_t)i * D_] = f2bf(h);
    }
}

// ---------------------------------------------------------------------------
// Retention via MFMA. Q bf16 [M][D]; K,V f32 [M][D]; Out f32.
// Block = 256 thr (4 waves), one (64-row q-tile, head, batch).
// ---------------------------------------------------------------------------
__global__ __launch_bounds__(256)
void retention_mfma(const ushort_t* __restrict__ Qb, const float* __restrict__ Kk,
                    const float* __restrict__ V, const float* __restrict__ gammas,
                    float* __restrict__ Out) {
    __shared__ ushort_t Qs[64 * 72];   // rows n_local, cols d
    __shared__ ushort_t Ks[64 * 72];   // rows m_local, cols d
    __shared__ ushort_t Vt[64 * 72];   // rows hd,      cols m_local  (V^T)
    __shared__ ushort_t Ps[64 * 72];   // rows n_local, cols m_local
    const int tid = threadIdx.x;
    const int nt = blockIdx.x, h = blockIdx.y, b = blockIdx.z;
    const int n0 = nt * 64;
    const float lg = log2f(gammas[h]);
    const int w = tid >> 6, lane = tid & 63, quad = lane >> 4, l15 = lane & 15;
    const int r = tid >> 2, c0 = (tid & 3) * 16;   // staging: row 0..63, col 0..48

    // stage Q tile (bf16 source, straight copy; 16 ushorts = 2 x uint4)
    {
        const ushort_t* qsrc = Qb + ((size_t)(b * S_ + n0 + r)) * D_ + h * HD_ + c0;
        *(uint4*)&Qs[r * 72 + c0 + 0] = *(const uint4*)(qsrc + 0);
        *(uint4*)&Qs[r * 72 + c0 + 8] = *(const uint4*)(qsrc + 8);
    }
    __syncthreads();
    // hoist Q fragments (invariant over m-tiles and ct)
    bf16x8 qf[2];
    #pragma unroll
    for (int kk = 0; kk < 2; ++kk)
        qf[kk] = *(const bf16x8*)&Qs[(w * 16 + l15) * 72 + kk * 32 + quad * 8];

    f32x4 o[4] = {};

    for (int mt = 0; mt <= nt; ++mt) {
        const int m0 = mt * 64;
        const float* ksrc = Kk + ((size_t)(b * S_ + m0 + r)) * D_ + h * HD_ + c0;
        const float* vsrc = V  + ((size_t)(b * S_ + m0 + r)) * D_ + h * HD_ + c0;
        float4 k0f = *(const float4*)(ksrc + 0),  k1f = *(const float4*)(ksrc + 4);
        float4 k2f = *(const float4*)(ksrc + 8),  k3f = *(const float4*)(ksrc + 12);
        float4 v0f = *(const float4*)(vsrc + 0),  v1f = *(const float4*)(vsrc + 4);
        float4 v2f = *(const float4*)(vsrc + 8),  v3f = *(const float4*)(vsrc + 12);
        __syncthreads();   // previous iteration's LDS reads complete
        {
            uint4 p0, p1;
            p0.x = pk2(k0f.x, k0f.y); p0.y = pk2(k0f.z, k0f.w);
            p0.z = pk2(k1f.x, k1f.y); p0.w = pk2(k1f.z, k1f.w);
            p1.x = pk2(k2f.x, k2f.y); p1.y = pk2(k2f.z, k2f.w);
            p1.z = pk2(k3f.x, k3f.y); p1.w = pk2(k3f.z, k3f.w);
            *(uint4*)&Ks[r * 72 + c0 + 0] = p0;
            *(uint4*)&Ks[r * 72 + c0 + 8] = p1;
            float vf[16] = {v0f.x, v0f.y, v0f.z, v0f.w, v1f.x, v1f.y, v1f.z, v1f.w,
                            v2f.x, v2f.y, v2f.z, v2f.w, v3f.x, v3f.y, v3f.z, v3f.w};
            #pragma unroll
            for (int j = 0; j < 16; ++j)
                Vt[(c0 + j) * 72 + r] = f2bf(vf[j]);
        }
        __syncthreads();

        // S = Q.K^T, decay-weight, write P (bf16) to LDS in A-operand layout
        #pragma unroll
        for (int ct = 0; ct < 4; ++ct) {
            f32x4 s = {};
            #pragma unroll
            for (int kk = 0; kk < 2; ++kk) {
                bf16x8 bk = *(const bf16x8*)&Ks[(ct * 16 + l15) * 72 + kk * 32 + quad * 8];
                s = __builtin_amdgcn_mfma_f32_16x16x32_bf16(qf[kk], bk, s, 0, 0, 0);
            }
            const int mloc = ct * 16 + l15;
            const int nbase = n0 + w * 16 + quad * 4;
            #pragma unroll
            for (int reg = 0; reg < 4; ++reg) {
                const int delta = nbase + reg - (m0 + mloc);
                const float wt = (delta >= 0) ? exp2f((float)delta * lg) * 0.125f : 0.0f;
                Ps[(w * 16 + quad * 4 + reg) * 72 + mloc] = f2bf(s[reg] * wt);
            }
        }
        __syncthreads();

        // O += P.V
        #pragma unroll
        for (int ct = 0; ct < 4; ++ct) {
            #pragma unroll
            for (int kk = 0; kk < 2; ++kk) {
                bf16x8 ap = *(const bf16x8*)&Ps[(w * 16 + l15) * 72 + kk * 32 + quad * 8];
                bf16x8 bv = *(const bf16x8*)&Vt[(ct * 16 + l15) * 72 + kk * 32 + quad * 8];
                o[ct] = __builtin_amdgcn_mfma_f32_16x16x32_bf16(ap, bv, o[ct], 0, 0, 0);
            }
        }
    }

    #pragma unroll
    for (int ct = 0; ct < 4; ++ct) {
        #pragma unroll
        for (int reg = 0; reg < 4; ++reg) {
            const int n = n0 + w * 16 + quad * 4 + reg;
            Out[((size_t)(b * S_ + n)) * D_ + h * HD_ + ct * 16 + l15] = o[ct][reg];
        }
    }
}

// ---------------------------------------------------------------------------
extern "C" void kernel_launch(void* const* d_in, const int* in_sizes, int n_in,
                              void* d_out, int out_size, void* d_ws, size_t ws_size,
                              hipStream_t stream) {
    const float* q      = (const float*)d_in[0];
    const float* k      = (const float*)d_in[1];
    const float* v      = (const float*)d_in[2];
    const float* W_in   = (const float*)d_in[3];
    const float* b_in   = (const float*)d_in[4];
    const float* W_gate = (const float*)d_in[5];
    const float* b_gate = (const float*)d_in[6];
    const float* W_out  = (const float*)d_in[7];
    const float* b_out  = (const float*)d_in[8];
    const float* gammas = (const float*)d_in[9];
    float* out = (float*)d_out;

    char* ws = (char*)d_ws;
    const size_t MB = 1024 * 1024;
    float*    a_buf   = (float*)(ws);                 // 16 MB
    ushort_t* u_bf    = (ushort_t*)(ws + 16 * MB);    //  8 MB
    ushort_t* h_bf    = (ushort_t*)(ws + 24 * MB);    //  8 MB
    ushort_t* q_bf    = (ushort_t*)(ws + 32 * MB);    //  8 MB
    ushort_t* WT_in   = (ushort_t*)(ws + 40 * MB);    //  2 MB
    ushort_t* WT_gate = (ushort_t*)(ws + 42 * MB);    //  2 MB
    ushort_t* WT_out  = (ushort_t*)(ws + 44 * MB);    //  2 MB
    float*    cA      = (float*)(ws + 46 * MB);       // 256 KB
    float*    cU      = (float*)(ws + 46 * MB + 256 * 1024);
    float*    cIn     = (float*)(ws + 46 * MB + 512 * 1024);
    ushort_t* qp_bf   = q_bf;   // alias: q_bf dead after gemm2

    dim3 tgrid(D_ / 32, D_ / 32);
    transp_cvt<<<tgrid, 256, 0, stream>>>(W_in,   WT_in);
    transp_cvt<<<tgrid, 256, 0, stream>>>(W_gate, WT_gate);
    transp_cvt<<<tgrid, 256, 0, stream>>>(W_out,  WT_out);
    cvt_bf16<<<(M_ * D_) / (256 * 4), 256, 0, stream>>>(q, q_bf);

    dim3 ggrid(D_ / 128, M_ / 128);
    gemm_mfma<0, 1><<<ggrid, 256, 0, stream>>>(q_bf, WT_in,   b_in,   nullptr, u_bf);
    gemm_mfma<1, 0><<<ggrid, 256, 0, stream>>>(q_bf, WT_gate, b_gate, a_buf,   nullptr);

    scan_pass1<<<(B_ * CH_ * D_) / 256, 256, 0, stream>>>(a_buf, u_bf, cA, cU);
    scan_pass2<<<(B_ * D_) / 256, 256, 0, stream>>>(cA, cU, cIn);
    scan_pass3<<<(B_ * CH_ * D_) / 256, 256, 0, stream>>>(a_buf, u_bf, cIn, h_bf);

    gemm_mfma<0, 1><<<ggrid, 256, 0, stream>>>(h_bf, WT_out, b_out, nullptr, qp_bf);

    retention_mfma<<<dim3(S_ / 64, H_, B_), 256, 0, stream>>>(qp_bf, k, v, gammas, out);
}

// Round 4
// 246.460 us; speedup vs baseline: 3.9015x; 1.3132x over previous
//
#include <hip/hip_runtime.h>
#include <math.h>

#define B_  2
#define S_  2048
#define D_  1024
#define H_  16
#define HD_ 64
#define M_  (B_*S_)      // 4096 rows in the GEMMs
#define CH_ 32           // scan chunks per sequence
#define CL_ 64           // scan chunk length (CH_*CL_ == S_)

typedef unsigned short ushort_t;
typedef unsigned int   uint_t;
typedef __attribute__((ext_vector_type(8))) short bf16x8;
typedef __attribute__((ext_vector_type(4))) float f32x4;

__device__ __forceinline__ ushort_t f2bf(float f) {
    uint_t u = __builtin_bit_cast(uint_t, f);
    u += 0x7FFFu + ((u >> 16) & 1u);           // RNE
    return (ushort_t)(u >> 16);
}
__device__ __forceinline__ float bf2f(ushort_t h) {
    uint_t u = (uint_t)h << 16;
    return __builtin_bit_cast(float, u);
}

// ---------------------------------------------------------------------------
// Transpose + convert: W [K=1024][N=1024] f32 -> WT [N][K] bf16
// ---------------------------------------------------------------------------
__global__ __launch_bounds__(256)
void transp_cvt(const float* __restrict__ W, ushort_t* __restrict__ WT) {
    __shared__ float T[32][36];
    const int kt = blockIdx.x, nt = blockIdx.y;
    const int t = threadIdx.x;
    const int rr = t >> 3, cc = (t & 7) * 4;
    float4 w4 = *(const float4*)(W + (size_t)(kt * 32 + rr) * D_ + nt * 32 + cc);
    T[rr][cc + 0] = w4.x; T[rr][cc + 1] = w4.y; T[rr][cc + 2] = w4.z; T[rr][cc + 3] = w4.w;
    __syncthreads();
    ushort_t o[4];
    #pragma unroll
    for (int j = 0; j < 4; ++j) o[j] = f2bf(T[cc + j][rr]);
    *(ushort4*)(WT + (size_t)(nt * 32 + rr) * D_ + kt * 32 + cc) =
        make_ushort4(o[0], o[1], o[2], o[3]);
}

// ---------------------------------------------------------------------------
// Elementwise convert f32 -> bf16
// ---------------------------------------------------------------------------
__global__ __launch_bounds__(256)
void cvt_bf16(const float* __restrict__ X, ushort_t* __restrict__ Y) {
    const int i = (blockIdx.x * 256 + threadIdx.x) * 4;
    float4 x = *(const float4*)(X + i);
    *(ushort4*)(Y + i) = make_ushort4(f2bf(x.x), f2bf(x.y), f2bf(x.z), f2bf(x.w));
}

// ---------------------------------------------------------------------------
// V [B,S,D] f32 -> VT [B,H,HD,S] bf16, scaled by gamma_h^{-(m&63)}
// ---------------------------------------------------------------------------
__global__ __launch_bounds__(256)
void vt_cvt(const float* __restrict__ V, const float* __restrict__ gammas,
            ushort_t* __restrict__ VT) {
    __shared__ ushort_t T[64 * 72];
    const int mt = blockIdx.x, h = blockIdx.y, b = blockIdx.z;
    const int m0 = mt * 64;
    const int tid = threadIdx.x;
    const int r = tid >> 2, c0 = (tid & 3) * 16;
    const float lg = log2f(gammas[h]);
    const float gm = exp2f(-(float)r * lg);   // (m0+r) & 63 == r
    const float* src = V + ((size_t)(b * S_ + m0 + r)) * D_ + h * HD_ + c0;
    #pragma unroll
    for (int j4 = 0; j4 < 4; ++j4) {
        float4 x = *(const float4*)(src + j4 * 4);
        T[(c0 + j4 * 4 + 0) * 72 + r] = f2bf(x.x * gm);
        T[(c0 + j4 * 4 + 1) * 72 + r] = f2bf(x.y * gm);
        T[(c0 + j4 * 4 + 2) * 72 + r] = f2bf(x.z * gm);
        T[(c0 + j4 * 4 + 3) * 72 + r] = f2bf(x.w * gm);
    }
    __syncthreads();
    ushort_t* dst = VT + ((size_t)((b * H_ + h) * HD_ + r)) * S_ + m0 + c0;
    *(uint4*)(dst + 0) = *(const uint4*)&T[r * 72 + c0 + 0];
    *(uint4*)(dst + 8) = *(const uint4*)&T[r * 72 + c0 + 8];
}

// ---------------------------------------------------------------------------
// bf16 MFMA GEMM: C[m,n] = act( A[m,:] . WT[n,:] + bias[n] ) * scale
// 128(M) x 64(N) tile, BK=64, 256 threads (4 waves, 2x2), 2 blocks/CU.
// ---------------------------------------------------------------------------
template <int ACT, int OUTBF>
__global__ __launch_bounds__(256)
void gemm_mfma(const ushort_t* __restrict__ A, const ushort_t* __restrict__ BT,
               const float* __restrict__ bias, float scale,
               float* __restrict__ Cf, ushort_t* __restrict__ Cb) {
    const int K = D_, N = D_;
    __shared__ ushort_t As[128 * 72];   // rows m, cols k, stride 72
    __shared__ ushort_t Bs[64 * 72];    // rows n, cols k
    const int tid = threadIdx.x;
    const int n0 = blockIdx.x * 64, m0 = blockIdx.y * 128;
    const int w = tid >> 6, lane = tid & 63, quad = lane >> 4, l15 = lane & 15;
    const int wr = (w >> 1) * 64, wc = (w & 1) * 32;
    const int sr = tid >> 1, sh = (tid & 1) * 32;   // A staging
    const int br = tid >> 2, bc = (tid & 3) * 16;   // B staging

    f32x4 acc[4][2] = {};
    const ushort_t* Ag = A  + (size_t)(m0 + sr) * K + sh;
    const ushort_t* Bg = BT + (size_t)(n0 + br) * K + bc;

    for (int k0 = 0; k0 < K; k0 += 64) {
        uint4 a0 = *(const uint4*)(Ag + k0 +  0);
        uint4 a1 = *(const uint4*)(Ag + k0 +  8);
        uint4 a2 = *(const uint4*)(Ag + k0 + 16);
        uint4 a3 = *(const uint4*)(Ag + k0 + 24);
        uint4 b0 = *(const uint4*)(Bg + k0 +  0);
        uint4 b1 = *(const uint4*)(Bg + k0 +  8);
        __syncthreads();
        *(uint4*)&As[sr * 72 + sh +  0] = a0;
        *(uint4*)&As[sr * 72 + sh +  8] = a1;
        *(uint4*)&As[sr * 72 + sh + 16] = a2;
        *(uint4*)&As[sr * 72 + sh + 24] = a3;
        *(uint4*)&Bs[br * 72 + bc +  0] = b0;
        *(uint4*)&Bs[br * 72 + bc +  8] = b1;
        __syncthreads();
        #pragma unroll
        for (int kk = 0; kk < 2; ++kk) {
            bf16x8 af[4], bf[2];
            #pragma unroll
            for (int i = 0; i < 4; ++i)
                af[i] = *(const bf16x8*)&As[(wr + 16 * i + l15) * 72 + kk * 32 + quad * 8];
            #pragma unroll
            for (int j = 0; j < 2; ++j)
                bf[j] = *(const bf16x8*)&Bs[(wc + 16 * j + l15) * 72 + kk * 32 + quad * 8];
            #pragma unroll
            for (int i = 0; i < 4; ++i)
                #pragma unroll
                for (int j = 0; j < 2; ++j)
                    acc[i][j] = __builtin_amdgcn_mfma_f32_16x16x32_bf16(
                        af[i], bf[j], acc[i][j], 0, 0, 0);
        }
    }

    #pragma unroll
    for (int j = 0; j < 2; ++j) {
        const int n = n0 + wc + 16 * j + l15;
        const float bb = bias[n];
        #pragma unroll
        for (int i = 0; i < 4; ++i) {
            #pragma unroll
            for (int r = 0; r < 4; ++r) {
                const int m = m0 + wr + 16 * i + quad * 4 + r;
                float x = acc[i][j][r] + bb;
                if (ACT == 1) x = 1.0f / (1.0f + __expf(-x));
                x *= scale;
                if (OUTBF) Cb[(size_t)m * N + n] = f2bf(x);
                else       Cf[(size_t)m * N + n] = x;
            }
        }
    }
}

// ---------------------------------------------------------------------------
// Chunked gated scan: h_t = a_t * h_{t-1} + u_t.  a f32, u bf16, h out bf16.
// ---------------------------------------------------------------------------
__global__ __launch_bounds__(256)
void scan_pass1(const float* __restrict__ a, const ushort_t* __restrict__ u,
                float* __restrict__ cA, float* __restrict__ cU) {
    const int tid = blockIdx.x * blockDim.x + threadIdx.x;
    const int d = tid % D_;
    const int c = (tid / D_) % CH_;
    const int b = tid / (D_ * CH_);
    size_t base = ((size_t)b * S_ + (size_t)c * CL_) * D_ + d;
    float A = 1.0f, h = 0.0f;
    for (int i = 0; i < CL_; ++i) {
        float av = a[base + (size_t)i * D_];
        float uv = bf2f(u[base + (size_t)i * D_]);
        A *= av;
        h = fmaf(av, h, uv);
    }
    cA[tid] = A;
    cU[tid] = h;
}

__global__ __launch_bounds__(256)
void scan_pass2(const float* __restrict__ cA, const float* __restrict__ cU,
                float* __restrict__ cIn) {
    const int tid = blockIdx.x * blockDim.x + threadIdx.x;
    const int d = tid % D_;
    const int b = tid / D_;
    float h = 0.0f;
    for (int c = 0; c < CH_; ++c) {
        const int idx = (b * CH_ + c) * D_ + d;
        float A = cA[idx], U = cU[idx];
        cIn[idx] = h;
        h = fmaf(A, h, U);
    }
}

__global__ __launch_bounds__(256)
void scan_pass3(const float* __restrict__ a, const ushort_t* __restrict__ u,
                const float* __restrict__ cIn, ushort_t* __restrict__ hout) {
    const int tid = blockIdx.x * blockDim.x + threadIdx.x;
    const int d = tid % D_;
    const int c = (tid / D_) % CH_;
    const int b = tid / (D_ * CH_);
    size_t base = ((size_t)b * S_ + (size_t)c * CL_) * D_ + d;
    float h = cIn[tid];
    for (int i = 0; i < CL_; ++i) {
        float av = a[base + (size_t)i * D_];
        float uv = bf2f(u[base + (size_t)i * D_]);
        h = fmaf(av, h, uv);
        hout[base + (size_t)i * D_] = f2bf(h);
    }
}

// ---------------------------------------------------------------------------
// Retention v2. Qb (pre-scaled by 1/8) bf16 [B,S,D]; Kb bf16 [B,S,D];
// VT bf16 [B,H,HD,S] pre-scaled by gamma^{-(m&63)}.
// Decay handled by O <- O*gamma^64 + C_t recurrence + exp2(nloc*lg) epilogue.
// Grid x remapped so each CU's 4 blocks have constant total work.
// ---------------------------------------------------------------------------
__global__ __launch_bounds__(256)
void retention_mfma2(const ushort_t* __restrict__ Qb, const ushort_t* __restrict__ Kb,
                     const ushort_t* __restrict__ VT, const float* __restrict__ gammas,
                     float* __restrict__ Out) {
    __shared__ ushort_t Qs[64 * 72];
    __shared__ ushort_t Ks[64 * 72];
    __shared__ ushort_t Vt[64 * 72];   // rows hd, cols mloc
    __shared__ ushort_t Ps[64 * 72];   // rows nloc, cols mloc
    const int tid = threadIdx.x;
    const int h = blockIdx.y, b = blockIdx.z;
    // load-balance swizzle: per-CU block set {x, 31-x, (x+16)&31, 31-((x+16)&31)}
    const int sw = (blockIdx.y >> 3) | (blockIdx.z << 1);
    const int xx = (sw & 2) ? ((blockIdx.x + 16) & 31) : blockIdx.x;
    const int nt = (sw & 1) ? (31 - xx) : xx;
    const int n0 = nt * 64;
    const float lg  = log2f(gammas[h]);
    const float g64 = exp2f(64.0f * lg);
    const int w = tid >> 6, lane = tid & 63, quad = lane >> 4, l15 = lane & 15;
    const int r = tid >> 2, c0 = (tid & 3) * 16;

    // stage Q tile (straight bf16 copy)
    {
        const ushort_t* qsrc = Qb + ((size_t)(b * S_ + n0 + r)) * D_ + h * HD_ + c0;
        *(uint4*)&Qs[r * 72 + c0 + 0] = *(const uint4*)(qsrc + 0);
        *(uint4*)&Qs[r * 72 + c0 + 8] = *(const uint4*)(qsrc + 8);
    }
    __syncthreads();
    bf16x8 qf[2];
    #pragma unroll
    for (int kk = 0; kk < 2; ++kk)
        qf[kk] = *(const bf16x8*)&Qs[(w * 16 + l15) * 72 + kk * 32 + quad * 8];

    f32x4 o[4] = {};
    const int prow = (w * 16 + quad * 4) * 72;   // Ps store row base
    const int nl0  = w * 16 + quad * 4;          // nloc base for this thread

    for (int mt = 0; mt <= nt; ++mt) {
        const int m0 = mt * 64;
        const ushort_t* ksrc = Kb + ((size_t)(b * S_ + m0 + r)) * D_ + h * HD_ + c0;
        const ushort_t* vsrc = VT + ((size_t)((b * H_ + h) * HD_ + r)) * S_ + m0 + c0;
        uint4 k0v = *(const uint4*)(ksrc + 0);
        uint4 k1v = *(const uint4*)(ksrc + 8);
        uint4 v0v = *(const uint4*)(vsrc + 0);
        uint4 v1v = *(const uint4*)(vsrc + 8);
        __syncthreads();   // previous iteration's LDS reads complete
        *(uint4*)&Ks[r * 72 + c0 + 0] = k0v;
        *(uint4*)&Ks[r * 72 + c0 + 8] = k1v;
        *(uint4*)&Vt[r * 72 + c0 + 0] = v0v;
        *(uint4*)&Vt[r * 72 + c0 + 8] = v1v;
        __syncthreads();

        // S = Q.K^T -> Ps (A-operand layout). Mask only on the diagonal tile.
        if (mt < nt) {
            #pragma unroll
            for (int ct = 0; ct < 4; ++ct) {
                f32x4 s = {};
                #pragma unroll
                for (int kk = 0; kk < 2; ++kk) {
                    bf16x8 bk = *(const bf16x8*)&Ks[(ct * 16 + l15) * 72 + kk * 32 + quad * 8];
                    s = __builtin_amdgcn_mfma_f32_16x16x32_bf16(qf[kk], bk, s, 0, 0, 0);
                }
                const int mloc = ct * 16 + l15;
                #pragma unroll
                for (int reg = 0; reg < 4; ++reg)
                    Ps[prow + reg * 72 + mloc] = f2bf(s[reg]);
            }
        } else {
            #pragma unroll
            for (int ct = 0; ct < 4; ++ct) {
                f32x4 s = {};
                #pragma unroll
                for (int kk = 0; kk < 2; ++kk) {
                    bf16x8 bk = *(const bf16x8*)&Ks[(ct * 16 + l15) * 72 + kk * 32 + quad * 8];
                    s = __builtin_amdgcn_mfma_f32_16x16x32_bf16(qf[kk], bk, s, 0, 0, 0);
                }
                const int mloc = ct * 16 + l15;
                #pragma unroll
                for (int reg = 0; reg < 4; ++reg)
                    Ps[prow + reg * 72 + mloc] = (nl0 + reg >= mloc) ? f2bf(s[reg]) : (ushort_t)0;
            }
        }

        // O = O*g64 + P.V   (Ps is wave-private: rows [w*16, w*16+16) r/w by wave w only)
        bf16x8 pf[2];
        #pragma unroll
        for (int kk = 0; kk < 2; ++kk)
            pf[kk] = *(const bf16x8*)&Ps[(w * 16 + l15) * 72 + kk * 32 + quad * 8];
        #pragma unroll
        for (int ct = 0; ct < 4; ++ct) {
            o[ct] = o[ct] * g64;
            #pragma unroll
            for (int kk = 0; kk < 2; ++kk) {
                bf16x8 bv = *(const bf16x8*)&Vt[(ct * 16 + l15) * 72 + kk * 32 + quad * 8];
                o[ct] = __builtin_amdgcn_mfma_f32_16x16x32_bf16(pf[kk], bv, o[ct], 0, 0, 0);
            }
        }
    }

    float esc[4];
    #pragma unroll
    for (int reg = 0; reg < 4; ++reg)
        esc[reg] = exp2f((float)(nl0 + reg) * lg);
    #pragma unroll
    for (int ct = 0; ct < 4; ++ct) {
        #pragma unroll
        for (int reg = 0; reg < 4; ++reg) {
            const int n = n0 + nl0 + reg;
            Out[((size_t)(b * S_ + n)) * D_ + h * HD_ + ct * 16 + l15] = o[ct][reg] * esc[reg];
        }
    }
}

// ---------------------------------------------------------------------------
extern "C" void kernel_launch(void* const* d_in, const int* in_sizes, int n_in,
                              void* d_out, int out_size, void* d_ws, size_t ws_size,
                              hipStream_t stream) {
    const float* q      = (const float*)d_in[0];
    const float* k      = (const float*)d_in[1];
    const float* v      = (const float*)d_in[2];
    const float* W_in   = (const float*)d_in[3];
    const float* b_in   = (const float*)d_in[4];
    const float* W_gate = (const float*)d_in[5];
    const float* b_gate = (const float*)d_in[6];
    const float* W_out  = (const float*)d_in[7];
    const float* b_out  = (const float*)d_in[8];
    const float* gammas = (const float*)d_in[9];
    float* out = (float*)d_out;

    char* ws = (char*)d_ws;
    const size_t MB = 1024 * 1024;
    float*    a_buf   = (float*)(ws);                 // 16 MB (dead after scan)
    ushort_t* u_bf    = (ushort_t*)(ws + 16 * MB);    //  8 MB
    ushort_t* h_bf    = (ushort_t*)(ws + 24 * MB);    //  8 MB
    ushort_t* q_bf    = (ushort_t*)(ws + 32 * MB);    //  8 MB
    ushort_t* WT_in   = (ushort_t*)(ws + 40 * MB);    //  2 MB
    ushort_t* WT_gate = (ushort_t*)(ws + 42 * MB);    //  2 MB
    ushort_t* WT_out  = (ushort_t*)(ws + 44 * MB);    //  2 MB
    float*    cA      = (float*)(ws + 46 * MB);       // 256 KB
    float*    cU      = (float*)(ws + 46 * MB + 256 * 1024);
    float*    cIn     = (float*)(ws + 46 * MB + 512 * 1024);
    ushort_t* k_bf    = (ushort_t*)(ws);              // aliases a_buf (8 MB)
    ushort_t* VT      = (ushort_t*)(ws + 8 * MB);     // aliases a_buf (8 MB)
    ushort_t* qp_bf   = q_bf;                          // q_bf dead after gemm2

    dim3 tgrid(D_ / 32, D_ / 32);
    transp_cvt<<<tgrid, 256, 0, stream>>>(W_in,   WT_in);
    transp_cvt<<<tgrid, 256, 0, stream>>>(W_gate, WT_gate);
    transp_cvt<<<tgrid, 256, 0, stream>>>(W_out,  WT_out);
    cvt_bf16<<<(M_ * D_) / (256 * 4), 256, 0, stream>>>(q, q_bf);

    dim3 ggrid(D_ / 64, M_ / 128);
    gemm_mfma<0, 1><<<ggrid, 256, 0, stream>>>(q_bf, WT_in,   b_in,   1.0f, nullptr, u_bf);
    gemm_mfma<1, 0><<<ggrid, 256, 0, stream>>>(q_bf, WT_gate, b_gate, 1.0f, a_buf,  nullptr);

    scan_pass1<<<(B_ * CH_ * D_) / 256, 256, 0, stream>>>(a_buf, u_bf, cA, cU);
    scan_pass2<<<(B_ * D_) / 256, 256, 0, stream>>>(cA, cU, cIn);
    scan_pass3<<<(B_ * CH_ * D_) / 256, 256, 0, stream>>>(a_buf, u_bf, cIn, h_bf);

    // a_buf now dead -> reuse its space for k_bf and VT
    cvt_bf16<<<(M_ * D_) / (256 * 4), 256, 0, stream>>>(k, k_bf);
    vt_cvt<<<dim3(S_ / 64, H_, B_), 256, 0, stream>>>(v, gammas, VT);

    // q_proj scaled by 1/sqrt(HD) = 0.125 here
    gemm_mfma<0, 1><<<ggrid, 256, 0, stream>>>(h_bf, WT_out, b_out, 0.125f, nullptr, qp_bf);

    retention_mfma2<<<dim3(S_ / 64, H_, B_), 256, 0, stream>>>(qp_bf, k_bf, VT, gammas, out);
}

// Round 5
// 227.824 us; speedup vs baseline: 4.2207x; 1.0818x over previous
//
#include <hip/hip_runtime.h>
#include <math.h>

#define B_  2
#define S_  2048
#define D_  1024
#define H_  16
#define HD_ 64
#define M_  (B_*S_)      // 4096 rows in the GEMMs
#define CH_ 64           // scan chunks per sequence
#define CL_ 32           // scan chunk length (CH_*CL_ == S_)

typedef unsigned short ushort_t;
typedef unsigned int   uint_t;
typedef __attribute__((ext_vector_type(8))) short bf16x8;
typedef __attribute__((ext_vector_type(4))) float f32x4;

__device__ __forceinline__ ushort_t f2bf(float f) {
    uint_t u = __builtin_bit_cast(uint_t, f);
    u += 0x7FFFu + ((u >> 16) & 1u);           // RNE
    return (ushort_t)(u >> 16);
}
__device__ __forceinline__ float bf2f(ushort_t h) {
    uint_t u = (uint_t)h << 16;
    return __builtin_bit_cast(float, u);
}
__device__ __forceinline__ uint_t pk2(float x, float y) {
    return (uint_t)f2bf(x) | ((uint_t)f2bf(y) << 16);
}

// ---------------------------------------------------------------------------
// Transpose + convert all three weights: W [K][N] f32 -> WT [N][K] bf16
// blockIdx.z selects the weight.
// ---------------------------------------------------------------------------
__global__ __launch_bounds__(256)
void transp_cvt3(const float* __restrict__ W0, const float* __restrict__ W1,
                 const float* __restrict__ W2, ushort_t* __restrict__ T0,
                 ushort_t* __restrict__ T1, ushort_t* __restrict__ T2) {
    __shared__ float T[32][36];
    const float*  W  = (blockIdx.z == 0) ? W0 : (blockIdx.z == 1) ? W1 : W2;
    ushort_t*     WT = (blockIdx.z == 0) ? T0 : (blockIdx.z == 1) ? T1 : T2;
    const int kt = blockIdx.x, nt = blockIdx.y;
    const int t = threadIdx.x;
    const int rr = t >> 3, cc = (t & 7) * 4;
    float4 w4 = *(const float4*)(W + (size_t)(kt * 32 + rr) * D_ + nt * 32 + cc);
    T[rr][cc + 0] = w4.x; T[rr][cc + 1] = w4.y; T[rr][cc + 2] = w4.z; T[rr][cc + 3] = w4.w;
    __syncthreads();
    ushort_t o[4];
    #pragma unroll
    for (int j = 0; j < 4; ++j) o[j] = f2bf(T[cc + j][rr]);
    *(ushort4*)(WT + (size_t)(nt * 32 + rr) * D_ + kt * 32 + cc) =
        make_ushort4(o[0], o[1], o[2], o[3]);
}

// ---------------------------------------------------------------------------
// Elementwise convert f32 -> bf16
// ---------------------------------------------------------------------------
__global__ __launch_bounds__(256)
void cvt_bf16(const float* __restrict__ X, ushort_t* __restrict__ Y) {
    const int i = (blockIdx.x * 256 + threadIdx.x) * 4;
    float4 x = *(const float4*)(X + i);
    *(ushort4*)(Y + i) = make_ushort4(f2bf(x.x), f2bf(x.y), f2bf(x.z), f2bf(x.w));
}

// ---------------------------------------------------------------------------
// K f32 -> Kb bf16 (straight), V f32 -> VT [B,H,HD,S] bf16 * gamma^{-(m&63)}
// ---------------------------------------------------------------------------
__global__ __launch_bounds__(256)
void kv_cvt(const float* __restrict__ K, const float* __restrict__ V,
            const float* __restrict__ gammas, ushort_t* __restrict__ Kb,
            ushort_t* __restrict__ VT) {
    __shared__ ushort_t T[64 * 72];
    const int mt = blockIdx.x, h = blockIdx.y, b = blockIdx.z;
    const int m0 = mt * 64;
    const int tid = threadIdx.x;
    const int r = tid >> 2, c0 = (tid & 3) * 16;
    const float lg = log2f(gammas[h]);
    const float gm = exp2f(-(float)r * lg);   // (m0+r) & 63 == r
    // K: straight convert, row-major
    {
        const float* src = K + ((size_t)(b * S_ + m0 + r)) * D_ + h * HD_ + c0;
        ushort_t kb[16];
        #pragma unroll
        for (int j4 = 0; j4 < 4; ++j4) {
            float4 x = *(const float4*)(src + j4 * 4);
            kb[j4 * 4 + 0] = f2bf(x.x); kb[j4 * 4 + 1] = f2bf(x.y);
            kb[j4 * 4 + 2] = f2bf(x.z); kb[j4 * 4 + 3] = f2bf(x.w);
        }
        ushort_t* dst = Kb + ((size_t)(b * S_ + m0 + r)) * D_ + h * HD_ + c0;
        *(uint4*)(dst + 0) = *(const uint4*)&kb[0];
        *(uint4*)(dst + 8) = *(const uint4*)&kb[8];
    }
    // V: scale + transpose via LDS
    {
        const float* src = V + ((size_t)(b * S_ + m0 + r)) * D_ + h * HD_ + c0;
        #pragma unroll
        for (int j4 = 0; j4 < 4; ++j4) {
            float4 x = *(const float4*)(src + j4 * 4);
            T[(c0 + j4 * 4 + 0) * 72 + r] = f2bf(x.x * gm);
            T[(c0 + j4 * 4 + 1) * 72 + r] = f2bf(x.y * gm);
            T[(c0 + j4 * 4 + 2) * 72 + r] = f2bf(x.z * gm);
            T[(c0 + j4 * 4 + 3) * 72 + r] = f2bf(x.w * gm);
        }
        __syncthreads();
        ushort_t* dst = VT + ((size_t)((b * H_ + h) * HD_ + r)) * S_ + m0 + c0;
        *(uint4*)(dst + 0) = *(const uint4*)&T[r * 72 + c0 + 0];
        *(uint4*)(dst + 8) = *(const uint4*)&T[r * 72 + c0 + 8];
    }
}

// ---------------------------------------------------------------------------
// Fused dual GEMM: u = A.WT_in + b_in (bf16 out); a = sigmoid(A.WT_gate+b_gate)
// 128(M) x 64(N) tile, BK=64, 256 threads (4 waves, 2x2). A staged once.
// ---------------------------------------------------------------------------
__global__ __launch_bounds__(256)
void gemm_dual(const ushort_t* __restrict__ A, const ushort_t* __restrict__ BTi,
               const ushort_t* __restrict__ BTg, const float* __restrict__ bi,
               const float* __restrict__ bg, ushort_t* __restrict__ U,
               float* __restrict__ G) {
    const int K = D_, N = D_;
    __shared__ ushort_t As[128 * 72];
    __shared__ ushort_t Bi[64 * 72];
    __shared__ ushort_t Bg[64 * 72];
    const int tid = threadIdx.x;
    const int n0 = blockIdx.x * 64, m0 = blockIdx.y * 128;
    const int w = tid >> 6, lane = tid & 63, quad = lane >> 4, l15 = lane & 15;
    const int wr = (w >> 1) * 64, wc = (w & 1) * 32;
    const int sr = tid >> 1, sh = (tid & 1) * 32;   // A staging
    const int br = tid >> 2, bc = (tid & 3) * 16;   // B staging

    f32x4 acc_i[4][2] = {};
    f32x4 acc_g[4][2] = {};
    const ushort_t* Ag  = A   + (size_t)(m0 + sr) * K + sh;
    const ushort_t* Bgi = BTi + (size_t)(n0 + br) * K + bc;
    const ushort_t* Bgg = BTg + (size_t)(n0 + br) * K + bc;

    for (int k0 = 0; k0 < K; k0 += 64) {
        uint4 a0 = *(const uint4*)(Ag + k0 +  0);
        uint4 a1 = *(const uint4*)(Ag + k0 +  8);
        uint4 a2 = *(const uint4*)(Ag + k0 + 16);
        uint4 a3 = *(const uint4*)(Ag + k0 + 24);
        uint4 i0 = *(const uint4*)(Bgi + k0 + 0);
        uint4 i1 = *(const uint4*)(Bgi + k0 + 8);
        uint4 g0 = *(const uint4*)(Bgg + k0 + 0);
        uint4 g1 = *(const uint4*)(Bgg + k0 + 8);
        __syncthreads();
        *(uint4*)&As[sr * 72 + sh +  0] = a0;
        *(uint4*)&As[sr * 72 + sh +  8] = a1;
        *(uint4*)&As[sr * 72 + sh + 16] = a2;
        *(uint4*)&As[sr * 72 + sh + 24] = a3;
        *(uint4*)&Bi[br * 72 + bc + 0] = i0;
        *(uint4*)&Bi[br * 72 + bc + 8] = i1;
        *(uint4*)&Bg[br * 72 + bc + 0] = g0;
        *(uint4*)&Bg[br * 72 + bc + 8] = g1;
        __syncthreads();
        #pragma unroll
        for (int kk = 0; kk < 2; ++kk) {
            bf16x8 af[4], bfi[2], bfg[2];
            #pragma unroll
            for (int i = 0; i < 4; ++i)
                af[i] = *(const bf16x8*)&As[(wr + 16 * i + l15) * 72 + kk * 32 + quad * 8];
            #pragma unroll
            for (int j = 0; j < 2; ++j) {
                bfi[j] = *(const bf16x8*)&Bi[(wc + 16 * j + l15) * 72 + kk * 32 + quad * 8];
                bfg[j] = *(const bf16x8*)&Bg[(wc + 16 * j + l15) * 72 + kk * 32 + quad * 8];
            }
            #pragma unroll
            for (int i = 0; i < 4; ++i)
                #pragma unroll
                for (int j = 0; j < 2; ++j) {
                    acc_i[i][j] = __builtin_amdgcn_mfma_f32_16x16x32_bf16(
                        af[i], bfi[j], acc_i[i][j], 0, 0, 0);
                    acc_g[i][j] = __builtin_amdgcn_mfma_f32_16x16x32_bf16(
                        af[i], bfg[j], acc_g[i][j], 0, 0, 0);
                }
        }
    }

    #pragma unroll
    for (int j = 0; j < 2; ++j) {
        const int n = n0 + wc + 16 * j + l15;
        const float bbi = bi[n], bbg = bg[n];
        #pragma unroll
        for (int i = 0; i < 4; ++i) {
            #pragma unroll
            for (int r = 0; r < 4; ++r) {
                const int m = m0 + wr + 16 * i + quad * 4 + r;
                U[(size_t)m * N + n] = f2bf(acc_i[i][j][r] + bbi);
                G[(size_t)m * N + n] = 1.0f / (1.0f + __expf(-(acc_g[i][j][r] + bbg)));
            }
        }
    }
}

// ---------------------------------------------------------------------------
// Single GEMM (for W_out): C = (A.WT + bias) * scale -> bf16
// ---------------------------------------------------------------------------
__global__ __launch_bounds__(256)
void gemm_mfma(const ushort_t* __restrict__ A, const ushort_t* __restrict__ BT,
               const float* __restrict__ bias, float scale,
               ushort_t* __restrict__ Cb) {
    const int K = D_, N = D_;
    __shared__ ushort_t As[128 * 72];
    __shared__ ushort_t Bs[64 * 72];
    const int tid = threadIdx.x;
    const int n0 = blockIdx.x * 64, m0 = blockIdx.y * 128;
    const int w = tid >> 6, lane = tid & 63, quad = lane >> 4, l15 = lane & 15;
    const int wr = (w >> 1) * 64, wc = (w & 1) * 32;
    const int sr = tid >> 1, sh = (tid & 1) * 32;
    const int br = tid >> 2, bc = (tid & 3) * 16;

    f32x4 acc[4][2] = {};
    const ushort_t* Ag = A  + (size_t)(m0 + sr) * K + sh;
    const ushort_t* Bg = BT + (size_t)(n0 + br) * K + bc;

    for (int k0 = 0; k0 < K; k0 += 64) {
        uint4 a0 = *(const uint4*)(Ag + k0 +  0);
        uint4 a1 = *(const uint4*)(Ag + k0 +  8);
        uint4 a2 = *(const uint4*)(Ag + k0 + 16);
        uint4 a3 = *(const uint4*)(Ag + k0 + 24);
        uint4 b0 = *(const uint4*)(Bg + k0 +  0);
        uint4 b1 = *(const uint4*)(Bg + k0 +  8);
        __syncthreads();
        *(uint4*)&As[sr * 72 + sh +  0] = a0;
        *(uint4*)&As[sr * 72 + sh +  8] = a1;
        *(uint4*)&As[sr * 72 + sh + 16] = a2;
        *(uint4*)&As[sr * 72 + sh + 24] = a3;
        *(uint4*)&Bs[br * 72 + bc + 0] = b0;
        *(uint4*)&Bs[br * 72 + bc + 8] = b1;
        __syncthreads();
        #pragma unroll
        for (int kk = 0; kk < 2; ++kk) {
            bf16x8 af[4], bf[2];
            #pragma unroll
            for (int i = 0; i < 4; ++i)
                af[i] = *(const bf16x8*)&As[(wr + 16 * i + l15) * 72 + kk * 32 + quad * 8];
            #pragma unroll
            for (int j = 0; j < 2; ++j)
                bf[j] = *(const bf16x8*)&Bs[(wc + 16 * j + l15) * 72 + kk * 32 + quad * 8];
            #pragma unroll
            for (int i = 0; i < 4; ++i)
                #pragma unroll
                for (int j = 0; j < 2; ++j)
                    acc[i][j] = __builtin_amdgcn_mfma_f32_16x16x32_bf16(
                        af[i], bf[j], acc[i][j], 0, 0, 0);
        }
    }

    #pragma unroll
    for (int j = 0; j < 2; ++j) {
        const int n = n0 + wc + 16 * j + l15;
        const float bb = bias[n];
        #pragma unroll
        for (int i = 0; i < 4; ++i) {
            #pragma unroll
            for (int r = 0; r < 4; ++r) {
                const int m = m0 + wr + 16 * i + quad * 4 + r;
                Cb[(size_t)m * N + n] = f2bf((acc[i][j][r] + bb) * scale);
            }
        }
    }
}

// ---------------------------------------------------------------------------
// Chunked gated scan, latency-optimized (batched independent loads).
// ---------------------------------------------------------------------------
__global__ __launch_bounds__(256)
void scan_pass1(const float* __restrict__ a, const ushort_t* __restrict__ u,
                float* __restrict__ cA, float* __restrict__ cU) {
    const int tid = blockIdx.x * blockDim.x + threadIdx.x;
    const int d = tid % D_;
    const int c = (tid / D_) % CH_;
    const int b = tid / (D_ * CH_);
    size_t base = ((size_t)b * S_ + (size_t)c * CL_) * D_ + d;
    float A = 1.0f, h = 0.0f;
    for (int i0 = 0; i0 < CL_; i0 += 8) {
        float av[8], uv[8];
        #pragma unroll
        for (int j = 0; j < 8; ++j) {
            av[j] = a[base + (size_t)(i0 + j) * D_];
            uv[j] = bf2f(u[base + (size_t)(i0 + j) * D_]);
        }
        #pragma unroll
        for (int j = 0; j < 8; ++j) {
            A *= av[j];
            h = fmaf(av[j], h, uv[j]);
        }
    }
    cA[tid] = A;
    cU[tid] = h;
}

__global__ __launch_bounds__(256)
void scan_pass2(const float* __restrict__ cA, const float* __restrict__ cU,
                float* __restrict__ cIn) {
    const int tid = blockIdx.x * blockDim.x + threadIdx.x;
    const int d = tid % D_;
    const int b = tid / D_;
    float h = 0.0f;
    for (int c0 = 0; c0 < CH_; c0 += 16) {
        float Av[16], Uv[16];
        #pragma unroll
        for (int j = 0; j < 16; ++j) {
            const int idx = (b * CH_ + c0 + j) * D_ + d;
            Av[j] = cA[idx];
            Uv[j] = cU[idx];
        }
        #pragma unroll
        for (int j = 0; j < 16; ++j) {
            cIn[(b * CH_ + c0 + j) * D_ + d] = h;
            h = fmaf(Av[j], h, Uv[j]);
        }
    }
}

__global__ __launch_bounds__(256)
void scan_pass3(const float* __restrict__ a, const ushort_t* __restrict__ u,
                const float* __restrict__ cIn, ushort_t* __restrict__ hout) {
    const int tid = blockIdx.x * blockDim.x + threadIdx.x;
    const int d = tid % D_;
    const int c = (tid / D_) % CH_;
    const int b = tid / (D_ * CH_);
    size_t base = ((size_t)b * S_ + (size_t)c * CL_) * D_ + d;
    float h = cIn[tid];
    for (int i0 = 0; i0 < CL_; i0 += 8) {
        float av[8], uv[8];
        #pragma unroll
        for (int j = 0; j < 8; ++j) {
            av[j] = a[base + (size_t)(i0 + j) * D_];
            uv[j] = bf2f(u[base + (size_t)(i0 + j) * D_]);
        }
        #pragma unroll
        for (int j = 0; j < 8; ++j) {
            h = fmaf(av[j], h, uv[j]);
            hout[base + (size_t)(i0 + j) * D_] = f2bf(h);
        }
    }
}

// ---------------------------------------------------------------------------
// Retention v3 (transposed): computes S^T = K.Q^T and O^T = VT.P^T.
// Qb pre-scaled by 1/8; VT pre-scaled by gamma^{-(m&63)}.
// O <- O*gamma^64 + C_t recurrence; epilogue scale gamma^{nloc}.
// P round-trip: thread's 4 S^T regs are m-contiguous -> one ds_write_b64.
// ---------------------------------------------------------------------------
__global__ __launch_bounds__(256)
void retention_mfma3(const ushort_t* __restrict__ Qb, const ushort_t* __restrict__ Kb,
                     const ushort_t* __restrict__ VT, const float* __restrict__ gammas,
                     float* __restrict__ Out) {
    __shared__ ushort_t Qs[64 * 72];   // rows nloc, cols d
    __shared__ ushort_t Ks[64 * 72];   // rows mloc, cols d
    __shared__ ushort_t Vt[64 * 72];   // rows hd,   cols mloc
    __shared__ ushort_t Ps[64 * 72];   // rows nloc, cols mloc  (= P, n-major)
    const int tid = threadIdx.x;
    const int h = blockIdx.y, b = blockIdx.z;
    // load-balance swizzle: per-CU block set has constant total work
    const int sw = (blockIdx.y >> 3) | (blockIdx.z << 1);
    const int xx = (sw & 2) ? ((blockIdx.x + 16) & 31) : blockIdx.x;
    const int nt = (sw & 1) ? (31 - xx) : xx;
    const int n0 = nt * 64;
    const float lg  = log2f(gammas[h]);
    const float g64 = exp2f(64.0f * lg);
    const int w = tid >> 6, lane = tid & 63, quad = lane >> 4, l15 = lane & 15;
    const int r = tid >> 2, c0 = (tid & 3) * 16;

    // stage Q tile
    {
        const ushort_t* qsrc = Qb + ((size_t)(b * S_ + n0 + r)) * D_ + h * HD_ + c0;
        *(uint4*)&Qs[r * 72 + c0 + 0] = *(const uint4*)(qsrc + 0);
        *(uint4*)&Qs[r * 72 + c0 + 8] = *(const uint4*)(qsrc + 8);
    }
    __syncthreads();
    // hoist Q fragments (B-operand; wave w owns n columns w*16+l15)
    const int nloc = w * 16 + l15;
    bf16x8 qf[2];
    #pragma unroll
    for (int kk = 0; kk < 2; ++kk)
        qf[kk] = *(const bf16x8*)&Qs[nloc * 72 + kk * 32 + quad * 8];

    f32x4 o[4] = {};
    const int psrow = nloc * 72;

    for (int mt = 0; mt <= nt; ++mt) {
        const int m0 = mt * 64;
        const ushort_t* ksrc = Kb + ((size_t)(b * S_ + m0 + r)) * D_ + h * HD_ + c0;
        const ushort_t* vsrc = VT + ((size_t)((b * H_ + h) * HD_ + r)) * S_ + m0 + c0;
        uint4 k0v = *(const uint4*)(ksrc + 0);
        uint4 k1v = *(const uint4*)(ksrc + 8);
        uint4 v0v = *(const uint4*)(vsrc + 0);
        uint4 v1v = *(const uint4*)(vsrc + 8);
        __syncthreads();   // previous iteration's LDS reads complete
        *(uint4*)&Ks[r * 72 + c0 + 0] = k0v;
        *(uint4*)&Ks[r * 72 + c0 + 8] = k1v;
        *(uint4*)&Vt[r * 72 + c0 + 0] = v0v;
        *(uint4*)&Vt[r * 72 + c0 + 8] = v1v;
        __syncthreads();

        // S^T[m][n] = K.Q^T : A = K rows (4 m-tiles), B = Q (hoisted)
        #pragma unroll
        for (int mt2 = 0; mt2 < 4; ++mt2) {
            f32x4 s = {};
            #pragma unroll
            for (int kk = 0; kk < 2; ++kk) {
                bf16x8 kf = *(const bf16x8*)&Ks[(mt2 * 16 + l15) * 72 + kk * 32 + quad * 8];
                s = __builtin_amdgcn_mfma_f32_16x16x32_bf16(kf, qf[kk], s, 0, 0, 0);
            }
            const int mbase = mt2 * 16 + quad * 4;   // m index of reg 0
            if (mt == nt) {                          // causal mask on diagonal tile
                #pragma unroll
                for (int reg = 0; reg < 4; ++reg)
                    if (nloc < mbase + reg) s[reg] = 0.0f;
            }
            uint2 pw;
            pw.x = pk2(s[0], s[1]);
            pw.y = pk2(s[2], s[3]);
            *(uint2*)&Ps[psrow + mbase] = pw;        // one b64 write
        }

        // O^T = O^T*g64 + VT.P^T : A = Vt rows (4 hd-tiles), B = Ps row nloc
        bf16x8 pf[2];
        #pragma unroll
        for (int kk = 0; kk < 2; ++kk)
            pf[kk] = *(const bf16x8*)&Ps[psrow + kk * 32 + quad * 8];
        #pragma unroll
        for (int ct = 0; ct < 4; ++ct) {
            o[ct] = o[ct] * g64;
            #pragma unroll
            for (int kk = 0; kk < 2; ++kk) {
                bf16x8 vf = *(const bf16x8*)&Vt[(ct * 16 + l15) * 72 + kk * 32 + quad * 8];
                o[ct] = __builtin_amdgcn_mfma_f32_16x16x32_bf16(vf, pf[kk], o[ct], 0, 0, 0);
            }
        }
    }

    const float esc = exp2f((float)nloc * lg);   // uniform over this thread's outputs
    const size_t orow = ((size_t)(b * S_ + n0 + nloc)) * D_ + h * HD_;
    #pragma unroll
    for (int ct = 0; ct < 4; ++ct) {
        float4 ov = make_float4(o[ct][0] * esc, o[ct][1] * esc,
                                o[ct][2] * esc, o[ct][3] * esc);
        *(float4*)(Out + orow + ct * 16 + quad * 4) = ov;
    }
}

// ---------------------------------------------------------------------------
extern "C" void kernel_launch(void* const* d_in, const int* in_sizes, int n_in,
                              void* d_out, int out_size, void* d_ws, size_t ws_size,
                              hipStream_t stream) {
    const float* q      = (const float*)d_in[0];
    const float* k      = (const float*)d_in[1];
    const float* v      = (const float*)d_in[2];
    const float* W_in   = (const float*)d_in[3];
    const float* b_in   = (const float*)d_in[4];
    const float* W_gate = (const float*)d_in[5];
    const float* b_gate = (const float*)d_in[6];
    const float* W_out  = (const float*)d_in[7];
    const float* b_out  = (const float*)d_in[8];
    const float* gammas = (const float*)d_in[9];
    float* out = (float*)d_out;

    char* ws = (char*)d_ws;
    const size_t MB = 1024 * 1024;
    float*    a_buf   = (float*)(ws);                 // 16 MB (dead after scan3)
    ushort_t* u_bf    = (ushort_t*)(ws + 16 * MB);    //  8 MB
    ushort_t* h_bf    = (ushort_t*)(ws + 24 * MB);    //  8 MB
    ushort_t* q_bf    = (ushort_t*)(ws + 32 * MB);    //  8 MB (dead after gemm_dual)
    ushort_t* WT_in   = (ushort_t*)(ws + 40 * MB);    //  2 MB (dead after gemm_dual)
    ushort_t* WT_gate = (ushort_t*)(ws + 42 * MB);    //  2 MB (dead after gemm_dual)
    ushort_t* WT_out  = (ushort_t*)(ws + 44 * MB);    //  2 MB
    // carries alias the dead WT_in/WT_gate region (512 KB each)
    float*    cA      = (float*)(ws + 40 * MB);
    float*    cU      = (float*)(ws + 40 * MB + 512 * 1024);
    float*    cIn     = (float*)(ws + 41 * MB);
    // k_bf / VT alias the dead a_buf region
    ushort_t* k_bf    = (ushort_t*)(ws);              // 8 MB
    ushort_t* VT      = (ushort_t*)(ws + 8 * MB);     // 8 MB
    ushort_t* qp_bf   = q_bf;

    transp_cvt3<<<dim3(D_ / 32, D_ / 32, 3), 256, 0, stream>>>(
        W_in, W_gate, W_out, WT_in, WT_gate, WT_out);
    cvt_bf16<<<(M_ * D_) / (256 * 4), 256, 0, stream>>>(q, q_bf);

    gemm_dual<<<dim3(D_ / 64, M_ / 128), 256, 0, stream>>>(
        q_bf, WT_in, WT_gate, b_in, b_gate, u_bf, a_buf);

    scan_pass1<<<(B_ * CH_ * D_) / 256, 256, 0, stream>>>(a_buf, u_bf, cA, cU);
    scan_pass2<<<(B_ * D_) / 256, 256, 0, stream>>>(cA, cU, cIn);
    scan_pass3<<<(B_ * CH_ * D_) / 256, 256, 0, stream>>>(a_buf, u_bf, cIn, h_bf);

    // a_buf dead -> k_bf + VT reuse its space
    kv_cvt<<<dim3(S_ / 64, H_, B_), 256, 0, stream>>>(k, v, gammas, k_bf, VT);

    // q_proj scaled by 1/sqrt(HD) = 0.125
    gemm_mfma<<<dim3(D_ / 64, M_ / 128), 256, 0, stream>>>(
        h_bf, WT_out, b_out, 0.125f, qp_bf);

    retention_mfma3<<<dim3(S_ / 64, H_, B_), 256, 0, stream>>>(
        qp_bf, k_bf, VT, gammas, out);
}

// Round 6
// 223.912 us; speedup vs baseline: 4.2944x; 1.0175x over previous
//
#include <hip/hip_runtime.h>
#include <math.h>

#define B_  2
#define S_  2048
#define D_  1024
#define H_  16
#define HD_ 64
#define M_  (B_*S_)

typedef unsigned short ushort_t;
typedef unsigned int   uint_t;
typedef __attribute__((ext_vector_type(8))) short bf16x8;
typedef __attribute__((ext_vector_type(4))) float f32x4;

__device__ __forceinline__ ushort_t f2bf(float f) {
    uint_t u = __builtin_bit_cast(uint_t, f);
    u += 0x7FFFu + ((u >> 16) & 1u);           // RNE
    return (ushort_t)(u >> 16);
}
__device__ __forceinline__ float bf2f(ushort_t h) {
    uint_t u = (uint_t)h << 16;
    return __builtin_bit_cast(float, u);
}
// truncating pack: two f32 -> (bf16(lo) | bf16(hi)<<16), one v_perm_b32
__device__ __forceinline__ uint_t pkt(float lo, float hi) {
    return __builtin_amdgcn_perm(__builtin_bit_cast(uint_t, hi),
                                 __builtin_bit_cast(uint_t, lo), 0x07060302u);
}
// async global->LDS, 16B per lane; lds must be wave-uniform-base + lane*16
__device__ __forceinline__ void dma16(const ushort_t* g, ushort_t* l) {
    __builtin_amdgcn_global_load_lds(
        (const __attribute__((address_space(1))) uint_t*)g,
        (__attribute__((address_space(3))) uint_t*)l, 16, 0, 0);
}
// swizzled fragment read from unpadded [row][64] bf16 tile
__device__ __forceinline__ bf16x8 fragr(const ushort_t* base, int row, int chunk) {
    return *(const bf16x8*)&base[row * 64 + (((chunk ^ (row & 7)) << 3))];
}

// ---------------------------------------------------------------------------
// Transpose + convert all three weights: W [K][N] f32 -> WT [N][K] bf16
// ---------------------------------------------------------------------------
__global__ __launch_bounds__(256)
void transp_cvt3(const float* __restrict__ W0, const float* __restrict__ W1,
                 const float* __restrict__ W2, ushort_t* __restrict__ T0,
                 ushort_t* __restrict__ T1, ushort_t* __restrict__ T2) {
    __shared__ float T[32][36];
    const float*  W  = (blockIdx.z == 0) ? W0 : (blockIdx.z == 1) ? W1 : W2;
    ushort_t*     WT = (blockIdx.z == 0) ? T0 : (blockIdx.z == 1) ? T1 : T2;
    const int kt = blockIdx.x, nt = blockIdx.y;
    const int t = threadIdx.x;
    const int rr = t >> 3, cc = (t & 7) * 4;
    float4 w4 = *(const float4*)(W + (size_t)(kt * 32 + rr) * D_ + nt * 32 + cc);
    T[rr][cc + 0] = w4.x; T[rr][cc + 1] = w4.y; T[rr][cc + 2] = w4.z; T[rr][cc + 3] = w4.w;
    __syncthreads();
    ushort_t o[4];
    #pragma unroll
    for (int j = 0; j < 4; ++j) o[j] = f2bf(T[cc + j][rr]);
    *(ushort4*)(WT + (size_t)(nt * 32 + rr) * D_ + kt * 32 + cc) =
        make_ushort4(o[0], o[1], o[2], o[3]);
}

__global__ __launch_bounds__(256)
void cvt_bf16(const float* __restrict__ X, ushort_t* __restrict__ Y) {
    const int i = (blockIdx.x * 256 + threadIdx.x) * 4;
    float4 x = *(const float4*)(X + i);
    *(ushort4*)(Y + i) = make_ushort4(f2bf(x.x), f2bf(x.y), f2bf(x.z), f2bf(x.w));
}

// ---------------------------------------------------------------------------
// K f32 -> Kb bf16 (straight), V f32 -> VT [B,H,HD,S] bf16 * gamma^{-(m&63)}
// ---------------------------------------------------------------------------
__global__ __launch_bounds__(256)
void kv_cvt(const float* __restrict__ K, const float* __restrict__ V,
            const float* __restrict__ gammas, ushort_t* __restrict__ Kb,
            ushort_t* __restrict__ VT) {
    __shared__ ushort_t T[64 * 72];
    const int mt = blockIdx.x, h = blockIdx.y, b = blockIdx.z;
    const int m0 = mt * 64;
    const int tid = threadIdx.x;
    const int r = tid >> 2, c0 = (tid & 3) * 16;
    const float lg = log2f(gammas[h]);
    const float gm = exp2f(-(float)r * lg);
    {
        const float* src = K + ((size_t)(b * S_ + m0 + r)) * D_ + h * HD_ + c0;
        ushort_t kb[16];
        #pragma unroll
        for (int j4 = 0; j4 < 4; ++j4) {
            float4 x = *(const float4*)(src + j4 * 4);
            kb[j4 * 4 + 0] = f2bf(x.x); kb[j4 * 4 + 1] = f2bf(x.y);
            kb[j4 * 4 + 2] = f2bf(x.z); kb[j4 * 4 + 3] = f2bf(x.w);
        }
        ushort_t* dst = Kb + ((size_t)(b * S_ + m0 + r)) * D_ + h * HD_ + c0;
        *(uint4*)(dst + 0) = *(const uint4*)&kb[0];
        *(uint4*)(dst + 8) = *(const uint4*)&kb[8];
    }
    {
        const float* src = V + ((size_t)(b * S_ + m0 + r)) * D_ + h * HD_ + c0;
        #pragma unroll
        for (int j4 = 0; j4 < 4; ++j4) {
            float4 x = *(const float4*)(src + j4 * 4);
            T[(c0 + j4 * 4 + 0) * 72 + r] = f2bf(x.x * gm);
            T[(c0 + j4 * 4 + 1) * 72 + r] = f2bf(x.y * gm);
            T[(c0 + j4 * 4 + 2) * 72 + r] = f2bf(x.z * gm);
            T[(c0 + j4 * 4 + 3) * 72 + r] = f2bf(x.w * gm);
        }
        __syncthreads();
        ushort_t* dst = VT + ((size_t)((b * H_ + h) * HD_ + r)) * S_ + m0 + c0;
        *(uint4*)(dst + 0) = *(const uint4*)&T[r * 72 + c0 + 0];
        *(uint4*)(dst + 8) = *(const uint4*)&T[r * 72 + c0 + 8];
    }
}

// ---------------------------------------------------------------------------
// Fused dual GEMM + per-chunk scan epilogue.
// u = A.WT_in + b_in; g = sigmoid(A.WT_gate + b_gate); then per (n, 32-chunk):
// serial scan -> Hloc (f32, uncorrected), Pp (bf16 prefix products), carries.
// 128(M) x 64(N) tile, BK=64, DMA staging into swizzled unpadded LDS.
// ---------------------------------------------------------------------------
__global__ __launch_bounds__(256)
void gemm_dual_scan(const ushort_t* __restrict__ A, const ushort_t* __restrict__ BTi,
                    const ushort_t* __restrict__ BTg, const float* __restrict__ bi,
                    const float* __restrict__ bg, float* __restrict__ Hloc,
                    ushort_t* __restrict__ Pp, float* __restrict__ cA,
                    float* __restrict__ cU) {
    __shared__ ushort_t smem[16384];      // As[0..8191] | Bi[8192..] | Bg[12288..]
    __shared__ float Gs[128 * 66];        // epilogue g (f32)
    ushort_t* As = smem;
    ushort_t* Bi = smem + 8192;
    ushort_t* Bg = smem + 12288;
    const int tid = threadIdx.x;
    const int n0 = blockIdx.x * 64, m0 = blockIdx.y * 128;
    const int w = tid >> 6, lane = tid & 63, quad = lane >> 4, l15 = lane & 15;
    const int wr = (w >> 1) * 64, wc = (w & 1) * 32;
    const int l8 = lane & 7, lr8 = lane >> 3;

    f32x4 acc_i[4][2] = {};
    f32x4 acc_g[4][2] = {};

    for (int k0 = 0; k0 < D_; k0 += 64) {
        __syncthreads();   // previous iteration's fragment reads complete
        #pragma unroll
        for (int t = 0; t < 4; ++t) {
            const int row = w * 32 + t * 8 + lr8;
            const int gc = ((l8 ^ (row & 7)) << 3);
            dma16(A + (size_t)(m0 + row) * D_ + k0 + gc, &As[row * 64 + l8 * 8]);
        }
        #pragma unroll
        for (int t = 0; t < 2; ++t) {
            const int row = w * 16 + t * 8 + lr8;
            const int gc = ((l8 ^ (row & 7)) << 3);
            dma16(BTi + (size_t)(n0 + row) * D_ + k0 + gc, &Bi[row * 64 + l8 * 8]);
            dma16(BTg + (size_t)(n0 + row) * D_ + k0 + gc, &Bg[row * 64 + l8 * 8]);
        }
        __syncthreads();   // drain DMA + barrier
        #pragma unroll
        for (int kk = 0; kk < 2; ++kk) {
            bf16x8 af[4], bfi[2], bfg[2];
            #pragma unroll
            for (int i = 0; i < 4; ++i)
                af[i] = fragr(As, wr + 16 * i + l15, kk * 4 + quad);
            #pragma unroll
            for (int j = 0; j < 2; ++j) {
                bfi[j] = fragr(Bi, wc + 16 * j + l15, kk * 4 + quad);
                bfg[j] = fragr(Bg, wc + 16 * j + l15, kk * 4 + quad);
            }
            #pragma unroll
            for (int i = 0; i < 4; ++i)
                #pragma unroll
                for (int j = 0; j < 2; ++j) {
                    acc_i[i][j] = __builtin_amdgcn_mfma_f32_16x16x32_bf16(
                        af[i], bfi[j], acc_i[i][j], 0, 0, 0);
                    acc_g[i][j] = __builtin_amdgcn_mfma_f32_16x16x32_bf16(
                        af[i], bfg[j], acc_g[i][j], 0, 0, 0);
                }
        }
    }

    __syncthreads();   // staging LDS dead; reuse As region for Us
    ushort_t* Us = smem;   // [128][66] bf16
    #pragma unroll
    for (int j = 0; j < 2; ++j) {
        const int n = wc + 16 * j + l15;
        const float bbi = bi[n0 + n], bbg = bg[n0 + n];
        #pragma unroll
        for (int i = 0; i < 4; ++i) {
            #pragma unroll
            for (int r = 0; r < 4; ++r) {
                const int m = wr + 16 * i + quad * 4 + r;
                Us[m * 66 + n] = f2bf(acc_i[i][j][r] + bbi);
                Gs[m * 66 + n] = 1.0f / (1.0f + __expf(-(acc_g[i][j][r] + bbg)));
            }
        }
    }
    __syncthreads();

    // per-thread serial scan over one 32-chunk of one channel
    const int nl = tid & 63, c = tid >> 6;
    const int gmb = m0 + c * 32;                       // global row of j=0
    const size_t gbase = (size_t)gmb * D_ + n0 + nl;
    float Aa = 1.0f, hh = 0.0f;
    #pragma unroll 4
    for (int j = 0; j < 32; ++j) {
        const float g = Gs[(c * 32 + j) * 66 + nl];
        const float u = bf2f(Us[(c * 32 + j) * 66 + nl]);
        Aa *= g;
        hh = fmaf(g, hh, u);
        Pp[gbase + (size_t)j * D_] = f2bf(Aa);
        Hloc[gbase + (size_t)j * D_] = hh;
    }
    const int bb = gmb >> 11;                          // batch
    const int ch = (gmb & 2047) >> 5;                  // chunk 0..63
    const int ci = ((bb * 64 + ch) << 10) + n0 + nl;
    cA[ci] = Aa;
    cU[ci] = hh;
}

// ---------------------------------------------------------------------------
// Chunk-level scan: 2048 channels, 64 chunks each.
// ---------------------------------------------------------------------------
__global__ __launch_bounds__(64)
void scan_pass2(const float* __restrict__ cA, const float* __restrict__ cU,
                float* __restrict__ cIn) {
    const int t = blockIdx.x * 64 + threadIdx.x;       // b*1024 + d
    const int d = t & 1023, b = t >> 10;
    float h = 0.0f;
    for (int c0 = 0; c0 < 64; c0 += 16) {
        float Av[16], Uv[16];
        #pragma unroll
        for (int j = 0; j < 16; ++j) {
            const int idx = ((b * 64 + c0 + j) << 10) + d;
            Av[j] = cA[idx]; Uv[j] = cU[idx];
        }
        #pragma unroll
        for (int j = 0; j < 16; ++j) {
            cIn[((b * 64 + c0 + j) << 10) + d] = h;
            h = fmaf(Av[j], h, Uv[j]);
        }
    }
}

// ---------------------------------------------------------------------------
// Elementwise fix: h = h_local + cIn[chunk] * P  -> bf16
// ---------------------------------------------------------------------------
__global__ __launch_bounds__(256)
void scan_fix(const float* __restrict__ Hloc, const ushort_t* __restrict__ Pp,
              const float* __restrict__ cIn, ushort_t* __restrict__ hout) {
    const int i = (blockIdx.x * 256 + threadIdx.x) * 4;
    const int m = i >> 10, d = i & 1023;
    const int b = m >> 11, ch = (m & 2047) >> 5;
    float4 hl = *(const float4*)(Hloc + i);
    ushort4 p4 = *(const ushort4*)(Pp + i);
    float4 ci = *(const float4*)(cIn + ((b * 64 + ch) << 10) + d);
    ushort4 o;
    o.x = f2bf(fmaf(ci.x, bf2f(p4.x), hl.x));
    o.y = f2bf(fmaf(ci.y, bf2f(p4.y), hl.y));
    o.z = f2bf(fmaf(ci.z, bf2f(p4.z), hl.z));
    o.w = f2bf(fmaf(ci.w, bf2f(p4.w), hl.w));
    *(ushort4*)(hout + i) = o;
}

// ---------------------------------------------------------------------------
// Single GEMM (W_out) with DMA staging: C = (A.WT + bias)*scale -> bf16
// ---------------------------------------------------------------------------
__global__ __launch_bounds__(256)
void gemm_out_a(const ushort_t* __restrict__ A, const ushort_t* __restrict__ BT,
                const float* __restrict__ bias, float scale,
                ushort_t* __restrict__ Cb) {
    __shared__ ushort_t As[8192];
    __shared__ ushort_t Bs[4096];
    const int tid = threadIdx.x;
    const int n0 = blockIdx.x * 64, m0 = blockIdx.y * 128;
    const int w = tid >> 6, lane = tid & 63, quad = lane >> 4, l15 = lane & 15;
    const int wr = (w >> 1) * 64, wc = (w & 1) * 32;
    const int l8 = lane & 7, lr8 = lane >> 3;

    f32x4 acc[4][2] = {};

    for (int k0 = 0; k0 < D_; k0 += 64) {
        __syncthreads();
        #pragma unroll
        for (int t = 0; t < 4; ++t) {
            const int row = w * 32 + t * 8 + lr8;
            const int gc = ((l8 ^ (row & 7)) << 3);
            dma16(A + (size_t)(m0 + row) * D_ + k0 + gc, &As[row * 64 + l8 * 8]);
        }
        #pragma unroll
        for (int t = 0; t < 2; ++t) {
            const int row = w * 16 + t * 8 + lr8;
            const int gc = ((l8 ^ (row & 7)) << 3);
            dma16(BT + (size_t)(n0 + row) * D_ + k0 + gc, &Bs[row * 64 + l8 * 8]);
        }
        __syncthreads();
        #pragma unroll
        for (int kk = 0; kk < 2; ++kk) {
            bf16x8 af[4], bf[2];
            #pragma unroll
            for (int i = 0; i < 4; ++i)
                af[i] = fragr(As, wr + 16 * i + l15, kk * 4 + quad);
            #pragma unroll
            for (int j = 0; j < 2; ++j)
                bf[j] = fragr(Bs, wc + 16 * j + l15, kk * 4 + quad);
            #pragma unroll
            for (int i = 0; i < 4; ++i)
                #pragma unroll
                for (int j = 0; j < 2; ++j)
                    acc[i][j] = __builtin_amdgcn_mfma_f32_16x16x32_bf16(
                        af[i], bf[j], acc[i][j], 0, 0, 0);
        }
    }

    #pragma unroll
    for (int j = 0; j < 2; ++j) {
        const int n = n0 + wc + 16 * j + l15;
        const float bb = bias[n];
        #pragma unroll
        for (int i = 0; i < 4; ++i)
            #pragma unroll
            for (int r = 0; r < 4; ++r) {
                const int m = m0 + wr + 16 * i + quad * 4 + r;
                Cb[(size_t)m * D_ + n] = f2bf((acc[i][j][r] + bb) * scale);
            }
    }
}

// ---------------------------------------------------------------------------
// Retention v4: 128-wide q-tile (two 64-halves per wave), DMA staging,
// per-tile decay scale folded into P (no accumulator rescaling),
// truncating v_perm pack. Qb pre-scaled 1/8; VT pre-scaled gamma^{-(m&63)}.
// ---------------------------------------------------------------------------
__global__ __launch_bounds__(256)
void retention_mfma4(const ushort_t* __restrict__ Qb, const ushort_t* __restrict__ Kb,
                     const ushort_t* __restrict__ VT, const float* __restrict__ gammas,
                     float* __restrict__ Out) {
    __shared__ ushort_t Qs[128 * 64];
    __shared__ ushort_t Ks[64 * 64];
    __shared__ ushort_t Vt[64 * 64];
    __shared__ ushort_t Ps[128 * 72];
    const int tid = threadIdx.x;
    const int h = blockIdx.y, b = blockIdx.z;
    const int ntx = (b == 1) ? (15 - blockIdx.x) : blockIdx.x;   // load balance
    const int n0 = ntx * 128;
    const float lg  = log2f(gammas[h]);
    const float g64 = exp2f(64.0f * lg);
    const int w = tid >> 6, lane = tid & 63, quad = lane >> 4, l15 = lane & 15;
    const int l8 = lane & 7, lr8 = lane >> 3;
    const int nl = w * 16 + l15;              // n within a 64-half
    const size_t bS = (size_t)b * S_;
    const size_t vrow0 = (size_t)((b * H_ + h) * HD_);

    // stage Q tile (128 rows)
    #pragma unroll
    for (int t = 0; t < 4; ++t) {
        const int row = w * 32 + t * 8 + lr8;
        const int gc = ((l8 ^ (row & 7)) << 3);
        dma16(Qb + (bS + n0 + row) * D_ + h * HD_ + gc, &Qs[row * 64 + l8 * 8]);
    }
    __syncthreads();
    bf16x8 qf[2][2];
    #pragma unroll
    for (int hf = 0; hf < 2; ++hf)
        #pragma unroll
        for (int kk = 0; kk < 2; ++kk)
            qf[hf][kk] = fragr(Qs, hf * 64 + nl, kk * 4 + quad);

    f32x4 o[2][4] = {};
    const int tl = 2 * ntx + 1;

    for (int mt = 0; mt <= tl; ++mt) {
        const int m0 = mt * 64;
        __syncthreads();   // previous iteration's reads complete
        #pragma unroll
        for (int t = 0; t < 2; ++t) {
            const int row = w * 16 + t * 8 + lr8;
            const int gc = ((l8 ^ (row & 7)) << 3);
            dma16(Kb + (bS + m0 + row) * D_ + h * HD_ + gc, &Ks[row * 64 + l8 * 8]);
            dma16(VT + (vrow0 + row) * S_ + m0 + gc, &Vt[row * 64 + l8 * 8]);
        }
        __syncthreads();

        const bool act0  = (mt <= 2 * ntx);
        const bool diag0 = (mt == 2 * ntx);
        const bool diag1 = (mt == tl);
        const float tsc0 = exp2f((float)(64 * (2 * ntx - mt)) * lg);
        const float tsc1 = tsc0 * g64;

        // S^T tiles -> scaled+masked P (bf16) in Ps
        #pragma unroll
        for (int mt2 = 0; mt2 < 4; ++mt2) {
            bf16x8 kf0 = fragr(Ks, mt2 * 16 + l15, quad);
            bf16x8 kf1 = fragr(Ks, mt2 * 16 + l15, 4 + quad);
            const int mbase = mt2 * 16 + quad * 4;
            if (act0) {
                f32x4 s = {};
                s = __builtin_amdgcn_mfma_f32_16x16x32_bf16(kf0, qf[0][0], s, 0, 0, 0);
                s = __builtin_amdgcn_mfma_f32_16x16x32_bf16(kf1, qf[0][1], s, 0, 0, 0);
                #pragma unroll
                for (int r = 0; r < 4; ++r) {
                    float v = s[r] * tsc0;
                    s[r] = (diag0 && nl < mbase + r) ? 0.0f : v;
                }
                uint2 pw; pw.x = pkt(s[0], s[1]); pw.y = pkt(s[2], s[3]);
                *(uint2*)&Ps[nl * 72 + mbase] = pw;
            }
            {
                f32x4 s = {};
                s = __builtin_amdgcn_mfma_f32_16x16x32_bf16(kf0, qf[1][0], s, 0, 0, 0);
                s = __builtin_amdgcn_mfma_f32_16x16x32_bf16(kf1, qf[1][1], s, 0, 0, 0);
                #pragma unroll
                for (int r = 0; r < 4; ++r) {
                    float v = s[r] * tsc1;
                    s[r] = (diag1 && nl < mbase + r) ? 0.0f : v;
                }
                uint2 pw; pw.x = pkt(s[0], s[1]); pw.y = pkt(s[2], s[3]);
                *(uint2*)&Ps[(64 + nl) * 72 + mbase] = pw;
            }
        }

        // O^T += Vt . P^T  (Ps rows are wave-private; no barrier needed)
        bf16x8 pf00, pf01, pf10, pf11;
        if (act0) {
            pf00 = *(const bf16x8*)&Ps[nl * 72 + quad * 8];
            pf01 = *(const bf16x8*)&Ps[nl * 72 + 32 + quad * 8];
        }
        pf10 = *(const bf16x8*)&Ps[(64 + nl) * 72 + quad * 8];
        pf11 = *(const bf16x8*)&Ps[(64 + nl) * 72 + 32 + quad * 8];
        #pragma unroll
        for (int ct = 0; ct < 4; ++ct) {
            bf16x8 vf0 = fragr(Vt, ct * 16 + l15, quad);
            bf16x8 vf1 = fragr(Vt, ct * 16 + l15, 4 + quad);
            if (act0) {
                o[0][ct] = __builtin_amdgcn_mfma_f32_16x16x32_bf16(vf0, pf00, o[0][ct], 0, 0, 0);
                o[0][ct] = __builtin_amdgcn_mfma_f32_16x16x32_bf16(vf1, pf01, o[0][ct], 0, 0, 0);
            }
            o[1][ct] = __builtin_amdgcn_mfma_f32_16x16x32_bf16(vf0, pf10, o[1][ct], 0, 0, 0);
            o[1][ct] = __builtin_amdgcn_mfma_f32_16x16x32_bf16(vf1, pf11, o[1][ct], 0, 0, 0);
        }
    }

    const float esc = exp2f((float)nl * lg);
    #pragma unroll
    for (int hf = 0; hf < 2; ++hf) {
        const size_t ob = (bS + n0 + hf * 64 + nl) * D_ + h * HD_;
        #pragma unroll
        for (int ct = 0; ct < 4; ++ct) {
            f32x4 t = o[hf][ct] * esc;
            *(f32x4*)(Out + ob + ct * 16 + quad * 4) = t;
        }
    }
}

// ---------------------------------------------------------------------------
extern "C" void kernel_launch(void* const* d_in, const int* in_sizes, int n_in,
                              void* d_out, int out_size, void* d_ws, size_t ws_size,
                              hipStream_t stream) {
    const float* q      = (const float*)d_in[0];
    const float* k      = (const float*)d_in[1];
    const float* v      = (const float*)d_in[2];
    const float* W_in   = (const float*)d_in[3];
    const float* b_in   = (const float*)d_in[4];
    const float* W_gate = (const float*)d_in[5];
    const float* b_gate = (const float*)d_in[6];
    const float* W_out  = (const float*)d_in[7];
    const float* b_out  = (const float*)d_in[8];
    const float* gammas = (const float*)d_in[9];
    float* out = (float*)d_out;

    char* ws = (char*)d_ws;
    const size_t MB = 1024 * 1024;
    float*    Hloc    = (float*)(ws);                 // 16 MB (dead after scan_fix)
    ushort_t* Pp      = (ushort_t*)(ws + 16 * MB);    //  8 MB (dead after scan_fix)
    ushort_t* h_bf    = (ushort_t*)(ws + 24 * MB);    //  8 MB
    ushort_t* q_bf    = (ushort_t*)(ws + 32 * MB);    //  8 MB (reused as qp_bf)
    ushort_t* WT_in   = (ushort_t*)(ws + 40 * MB);    //  2 MB
    ushort_t* WT_gate = (ushort_t*)(ws + 42 * MB);    //  2 MB
    ushort_t* WT_out  = (ushort_t*)(ws + 44 * MB);    //  2 MB
    float*    cA      = (float*)(ws + 46 * MB);       // 512 KB
    float*    cU      = (float*)(ws + 46 * MB + 512 * 1024);
    float*    cIn     = (float*)(ws + 47 * MB);
    ushort_t* k_bf    = (ushort_t*)(ws);              // aliases Hloc (8 MB)
    ushort_t* VT      = (ushort_t*)(ws + 8 * MB);     // aliases Hloc (8 MB)
    ushort_t* qp_bf   = q_bf;

    transp_cvt3<<<dim3(D_ / 32, D_ / 32, 3), 256, 0, stream>>>(
        W_in, W_gate, W_out, WT_in, WT_gate, WT_out);
    cvt_bf16<<<(M_ * D_) / (256 * 4), 256, 0, stream>>>(q, q_bf);

    gemm_dual_scan<<<dim3(D_ / 64, M_ / 128), 256, 0, stream>>>(
        q_bf, WT_in, WT_gate, b_in, b_gate, Hloc, Pp, cA, cU);

    scan_pass2<<<32, 64, 0, stream>>>(cA, cU, cIn);
    scan_fix<<<(M_ * D_) / 1024, 256, 0, stream>>>(Hloc, Pp, cIn, h_bf);

    // Hloc/Pp dead -> k_bf + VT reuse the front of the workspace
    kv_cvt<<<dim3(S_ / 64, H_, B_), 256, 0, stream>>>(k, v, gammas, k_bf, VT);

    gemm_out_a<<<dim3(D_ / 64, M_ / 128), 256, 0, stream>>>(
        h_bf, WT_out, b_out, 0.125f, qp_bf);

    retention_mfma4<<<dim3(S_ / 128, H_, B_), 256, 0, stream>>>(
        qp_bf, k_bf, VT, gammas, out);
}

// Round 7
// 218.067 us; speedup vs baseline: 4.4095x; 1.0268x over previous
//
#include <hip/hip_runtime.h>
#include <math.h>

#define B_  2
#define S_  2048
#define D_  1024
#define H_  16
#define HD_ 64
#define M_  (B_*S_)

typedef unsigned short ushort_t;
typedef unsigned int   uint_t;
typedef __attribute__((ext_vector_type(8))) short bf16x8;
typedef __attribute__((ext_vector_type(4))) float f32x4;

__device__ __forceinline__ ushort_t f2bf(float f) {
    uint_t u = __builtin_bit_cast(uint_t, f);
    u += 0x7FFFu + ((u >> 16) & 1u);           // RNE
    return (ushort_t)(u >> 16);
}
__device__ __forceinline__ float bf2f(ushort_t h) {
    uint_t u = (uint_t)h << 16;
    return __builtin_bit_cast(float, u);
}
// truncating pack: two f32 -> (bf16(lo) | bf16(hi)<<16), one v_perm_b32
__device__ __forceinline__ uint_t pkt(float lo, float hi) {
    return __builtin_amdgcn_perm(__builtin_bit_cast(uint_t, hi),
                                 __builtin_bit_cast(uint_t, lo), 0x07060302u);
}
// async global->LDS, 16B per lane; lds addr = wave-uniform base + lane*16
__device__ __forceinline__ void dma16(const ushort_t* g, ushort_t* l) {
    __builtin_amdgcn_global_load_lds(
        (const __attribute__((address_space(1))) uint_t*)g,
        (__attribute__((address_space(3))) uint_t*)l, 16, 0, 0);
}
// swizzled fragment read from unpadded [row][64] bf16 tile
__device__ __forceinline__ bf16x8 fragr(const ushort_t* base, int row, int chunk) {
    return *(const bf16x8*)&base[row * 64 + (((chunk ^ (row & 7)) << 3))];
}

// ---------------------------------------------------------------------------
// Transpose + convert all three weights: W [K][N] f32 -> WT [N][K] bf16
// ---------------------------------------------------------------------------
__global__ __launch_bounds__(256)
void transp_cvt3(const float* __restrict__ W0, const float* __restrict__ W1,
                 const float* __restrict__ W2, ushort_t* __restrict__ T0,
                 ushort_t* __restrict__ T1, ushort_t* __restrict__ T2) {
    __shared__ float T[32][36];
    const float*  W  = (blockIdx.z == 0) ? W0 : (blockIdx.z == 1) ? W1 : W2;
    ushort_t*     WT = (blockIdx.z == 0) ? T0 : (blockIdx.z == 1) ? T1 : T2;
    const int kt = blockIdx.x, nt = blockIdx.y;
    const int t = threadIdx.x;
    const int rr = t >> 3, cc = (t & 7) * 4;
    float4 w4 = *(const float4*)(W + (size_t)(kt * 32 + rr) * D_ + nt * 32 + cc);
    T[rr][cc + 0] = w4.x; T[rr][cc + 1] = w4.y; T[rr][cc + 2] = w4.z; T[rr][cc + 3] = w4.w;
    __syncthreads();
    ushort_t o[4];
    #pragma unroll
    for (int j = 0; j < 4; ++j) o[j] = f2bf(T[cc + j][rr]);
    *(ushort4*)(WT + (size_t)(nt * 32 + rr) * D_ + kt * 32 + cc) =
        make_ushort4(o[0], o[1], o[2], o[3]);
}

__global__ __launch_bounds__(256)
void cvt_bf16(const float* __restrict__ X, ushort_t* __restrict__ Y) {
    const int i = (blockIdx.x * 256 + threadIdx.x) * 4;
    float4 x = *(const float4*)(X + i);
    *(ushort4*)(Y + i) = make_ushort4(f2bf(x.x), f2bf(x.y), f2bf(x.z), f2bf(x.w));
}

// ---------------------------------------------------------------------------
// K f32 -> Kb bf16 (straight), V f32 -> VT [B,H,HD,S] bf16 * gamma^{-(m&63)}
// ---------------------------------------------------------------------------
__global__ __launch_bounds__(256)
void kv_cvt(const float* __restrict__ K, const float* __restrict__ V,
            const float* __restrict__ gammas, ushort_t* __restrict__ Kb,
            ushort_t* __restrict__ VT) {
    __shared__ ushort_t T[64 * 72];
    const int mt = blockIdx.x, h = blockIdx.y, b = blockIdx.z;
    const int m0 = mt * 64;
    const int tid = threadIdx.x;
    const int r = tid >> 2, c0 = (tid & 3) * 16;
    const float lg = log2f(gammas[h]);
    const float gm = exp2f(-(float)r * lg);
    {
        const float* src = K + ((size_t)(b * S_ + m0 + r)) * D_ + h * HD_ + c0;
        ushort_t kb[16];
        #pragma unroll
        for (int j4 = 0; j4 < 4; ++j4) {
            float4 x = *(const float4*)(src + j4 * 4);
            kb[j4 * 4 + 0] = f2bf(x.x); kb[j4 * 4 + 1] = f2bf(x.y);
            kb[j4 * 4 + 2] = f2bf(x.z); kb[j4 * 4 + 3] = f2bf(x.w);
        }
        ushort_t* dst = Kb + ((size_t)(b * S_ + m0 + r)) * D_ + h * HD_ + c0;
        *(uint4*)(dst + 0) = *(const uint4*)&kb[0];
        *(uint4*)(dst + 8) = *(const uint4*)&kb[8];
    }
    {
        const float* src = V + ((size_t)(b * S_ + m0 + r)) * D_ + h * HD_ + c0;
        #pragma unroll
        for (int j4 = 0; j4 < 4; ++j4) {
            float4 x = *(const float4*)(src + j4 * 4);
            T[(c0 + j4 * 4 + 0) * 72 + r] = f2bf(x.x * gm);
            T[(c0 + j4 * 4 + 1) * 72 + r] = f2bf(x.y * gm);
            T[(c0 + j4 * 4 + 2) * 72 + r] = f2bf(x.z * gm);
            T[(c0 + j4 * 4 + 3) * 72 + r] = f2bf(x.w * gm);
        }
        __syncthreads();
        ushort_t* dst = VT + ((size_t)((b * H_ + h) * HD_ + r)) * S_ + m0 + c0;
        *(uint4*)(dst + 0) = *(const uint4*)&T[r * 72 + c0 + 0];
        *(uint4*)(dst + 8) = *(const uint4*)&T[r * 72 + c0 + 8];
    }
}

// ---------------------------------------------------------------------------
// Fused dual GEMM + chunk-scan epilogue, double-buffered DMA staging.
// u = A.WT_in + b_in; g = sigmoid(A.WT_gate + b_gate); per (n, 32-chunk):
// serial scan -> Hloc (f32), Pp (bf16 prefix products), chunk carries.
// ---------------------------------------------------------------------------
__global__ __launch_bounds__(256)
void gemm_dual_scan(const ushort_t* __restrict__ A, const ushort_t* __restrict__ BTi,
                    const ushort_t* __restrict__ BTg, const float* __restrict__ bi,
                    const float* __restrict__ bg, float* __restrict__ Hloc,
                    ushort_t* __restrict__ Pp, float* __restrict__ cA,
                    float* __restrict__ cU) {
    __shared__ ushort_t smem[32768];   // 64 KB = 2 buffers x (As 8192 | Bi 4096 | Bg 4096)
    const int tid = threadIdx.x;
    const int n0 = blockIdx.x * 64, m0 = blockIdx.y * 128;
    const int w = tid >> 6, lane = tid & 63, quad = lane >> 4, l15 = lane & 15;
    const int wr = (w >> 1) * 64, wc = (w & 1) * 32;
    const int l8 = lane & 7, lr8 = lane >> 3;

    f32x4 acc_i[4][2] = {};
    f32x4 acc_g[4][2] = {};

    auto stage = [&](int k0, int bufo) {
        #pragma unroll
        for (int t = 0; t < 4; ++t) {
            const int row = w * 32 + t * 8 + lr8;
            const int gc = ((l8 ^ (row & 7)) << 3);
            dma16(A + (size_t)(m0 + row) * D_ + k0 + gc, &smem[bufo + row * 64 + l8 * 8]);
        }
        #pragma unroll
        for (int t = 0; t < 2; ++t) {
            const int row = w * 16 + t * 8 + lr8;
            const int gc = ((l8 ^ (row & 7)) << 3);
            dma16(BTi + (size_t)(n0 + row) * D_ + k0 + gc, &smem[bufo + 8192 + row * 64 + l8 * 8]);
            dma16(BTg + (size_t)(n0 + row) * D_ + k0 + gc, &smem[bufo + 12288 + row * 64 + l8 * 8]);
        }
    };

    stage(0, 0);
    __syncthreads();
    for (int t = 0; t < 16; ++t) {
        const int bufo = (t & 1) * 16384;
        if (t < 15) stage((t + 1) * 64, 16384 - bufo);   // prefetch next tile
        const ushort_t* As = smem + bufo;
        const ushort_t* Bi = smem + bufo + 8192;
        const ushort_t* Bg = smem + bufo + 12288;
        #pragma unroll
        for (int kk = 0; kk < 2; ++kk) {
            bf16x8 af[4], bfi[2], bfg[2];
            #pragma unroll
            for (int i = 0; i < 4; ++i)
                af[i] = fragr(As, wr + 16 * i + l15, kk * 4 + quad);
            #pragma unroll
            for (int j = 0; j < 2; ++j) {
                bfi[j] = fragr(Bi, wc + 16 * j + l15, kk * 4 + quad);
                bfg[j] = fragr(Bg, wc + 16 * j + l15, kk * 4 + quad);
            }
            #pragma unroll
            for (int i = 0; i < 4; ++i)
                #pragma unroll
                for (int j = 0; j < 2; ++j) {
                    acc_i[i][j] = __builtin_amdgcn_mfma_f32_16x16x32_bf16(
                        af[i], bfi[j], acc_i[i][j], 0, 0, 0);
                    acc_g[i][j] = __builtin_amdgcn_mfma_f32_16x16x32_bf16(
                        af[i], bfg[j], acc_g[i][j], 0, 0, 0);
                }
        }
        __syncthreads();   // drains prefetch DMA + protects buffer swap
    }

    // epilogue: reuse staging LDS. Us bf16 [128][66], Gu u16 fixed-point gate.
    ushort_t* Us = smem;
    ushort_t* Gu = smem + 8448;
    #pragma unroll
    for (int j = 0; j < 2; ++j) {
        const int n = wc + 16 * j + l15;
        const float bbi = bi[n0 + n], bbg = bg[n0 + n];
        #pragma unroll
        for (int i = 0; i < 4; ++i) {
            #pragma unroll
            for (int r = 0; r < 4; ++r) {
                const int m = wr + 16 * i + quad * 4 + r;
                Us[m * 66 + n] = f2bf(acc_i[i][j][r] + bbi);
                float g = 1.0f / (1.0f + __expf(-(acc_g[i][j][r] + bbg)));
                Gu[m * 66 + n] = (ushort_t)__float2uint_rn(g * 65535.0f);
            }
        }
    }
    __syncthreads();

    // per-thread serial scan over one 32-chunk of one channel
    const int nl = tid & 63, c = tid >> 6;
    const int gmb = m0 + c * 32;
    const size_t gbase = (size_t)gmb * D_ + n0 + nl;
    float Aa = 1.0f, hh = 0.0f;
    #pragma unroll 4
    for (int j = 0; j < 32; ++j) {
        const float g = (float)Gu[(c * 32 + j) * 66 + nl] * (1.0f / 65535.0f);
        const float u = bf2f(Us[(c * 32 + j) * 66 + nl]);
        Aa *= g;
        hh = fmaf(g, hh, u);
        Pp[gbase + (size_t)j * D_] = f2bf(Aa);
        Hloc[gbase + (size_t)j * D_] = hh;
    }
    const int bb = gmb >> 11;
    const int ch = (gmb & 2047) >> 5;
    const int ci = ((bb * 64 + ch) << 10) + n0 + nl;
    cA[ci] = Aa;
    cU[ci] = hh;
}

// ---------------------------------------------------------------------------
// Chunk-level scan: 2048 channels, 64 chunks each.
// ---------------------------------------------------------------------------
__global__ __launch_bounds__(64)
void scan_pass2(const float* __restrict__ cA, const float* __restrict__ cU,
                float* __restrict__ cIn) {
    const int t = blockIdx.x * 64 + threadIdx.x;
    const int d = t & 1023, b = t >> 10;
    float h = 0.0f;
    for (int c0 = 0; c0 < 64; c0 += 16) {
        float Av[16], Uv[16];
        #pragma unroll
        for (int j = 0; j < 16; ++j) {
            const int idx = ((b * 64 + c0 + j) << 10) + d;
            Av[j] = cA[idx]; Uv[j] = cU[idx];
        }
        #pragma unroll
        for (int j = 0; j < 16; ++j) {
            cIn[((b * 64 + c0 + j) << 10) + d] = h;
            h = fmaf(Av[j], h, Uv[j]);
        }
    }
}

// ---------------------------------------------------------------------------
// Elementwise fix: h = h_local + cIn[chunk] * P  -> bf16
// ---------------------------------------------------------------------------
__global__ __launch_bounds__(256)
void scan_fix(const float* __restrict__ Hloc, const ushort_t* __restrict__ Pp,
              const float* __restrict__ cIn, ushort_t* __restrict__ hout) {
    const int i = (blockIdx.x * 256 + threadIdx.x) * 4;
    const int m = i >> 10, d = i & 1023;
    const int b = m >> 11, ch = (m & 2047) >> 5;
    float4 hl = *(const float4*)(Hloc + i);
    ushort4 p4 = *(const ushort4*)(Pp + i);
    float4 ci = *(const float4*)(cIn + ((b * 64 + ch) << 10) + d);
    ushort4 o;
    o.x = f2bf(fmaf(ci.x, bf2f(p4.x), hl.x));
    o.y = f2bf(fmaf(ci.y, bf2f(p4.y), hl.y));
    o.z = f2bf(fmaf(ci.z, bf2f(p4.z), hl.z));
    o.w = f2bf(fmaf(ci.w, bf2f(p4.w), hl.w));
    *(ushort4*)(hout + i) = o;
}

// ---------------------------------------------------------------------------
// Single GEMM (W_out), double-buffered DMA: C = (A.WT + bias)*scale -> bf16
// ---------------------------------------------------------------------------
__global__ __launch_bounds__(256)
void gemm_out_a(const ushort_t* __restrict__ A, const ushort_t* __restrict__ BT,
                const float* __restrict__ bias, float scale,
                ushort_t* __restrict__ Cb) {
    __shared__ ushort_t smem[24576];   // 48 KB = 2 buffers x (As 8192 | Bs 4096)
    const int tid = threadIdx.x;
    const int n0 = blockIdx.x * 64, m0 = blockIdx.y * 128;
    const int w = tid >> 6, lane = tid & 63, quad = lane >> 4, l15 = lane & 15;
    const int wr = (w >> 1) * 64, wc = (w & 1) * 32;
    const int l8 = lane & 7, lr8 = lane >> 3;

    f32x4 acc[4][2] = {};

    auto stage = [&](int k0, int bufo) {
        #pragma unroll
        for (int t = 0; t < 4; ++t) {
            const int row = w * 32 + t * 8 + lr8;
            const int gc = ((l8 ^ (row & 7)) << 3);
            dma16(A + (size_t)(m0 + row) * D_ + k0 + gc, &smem[bufo + row * 64 + l8 * 8]);
        }
        #pragma unroll
        for (int t = 0; t < 2; ++t) {
            const int row = w * 16 + t * 8 + lr8;
            const int gc = ((l8 ^ (row & 7)) << 3);
            dma16(BT + (size_t)(n0 + row) * D_ + k0 + gc, &smem[bufo + 8192 + row * 64 + l8 * 8]);
        }
    };

    stage(0, 0);
    __syncthreads();
    for (int t = 0; t < 16; ++t) {
        const int bufo = (t & 1) * 12288;
        if (t < 15) stage((t + 1) * 64, 12288 - bufo);
        const ushort_t* As = smem + bufo;
        const ushort_t* Bs = smem + bufo + 8192;
        #pragma unroll
        for (int kk = 0; kk < 2; ++kk) {
            bf16x8 af[4], bf[2];
            #pragma unroll
            for (int i = 0; i < 4; ++i)
                af[i] = fragr(As, wr + 16 * i + l15, kk * 4 + quad);
            #pragma unroll
            for (int j = 0; j < 2; ++j)
                bf[j] = fragr(Bs, wc + 16 * j + l15, kk * 4 + quad);
            #pragma unroll
            for (int i = 0; i < 4; ++i)
                #pragma unroll
                for (int j = 0; j < 2; ++j)
                    acc[i][j] = __builtin_amdgcn_mfma_f32_16x16x32_bf16(
                        af[i], bf[j], acc[i][j], 0, 0, 0);
        }
        __syncthreads();
    }

    #pragma unroll
    for (int j = 0; j < 2; ++j) {
        const int n = n0 + wc + 16 * j + l15;
        const float bb = bias[n];
        #pragma unroll
        for (int i = 0; i < 4; ++i)
            #pragma unroll
            for (int r = 0; r < 4; ++r) {
                const int m = m0 + wr + 16 * i + quad * 4 + r;
                Cb[(size_t)m * D_ + n] = f2bf((acc[i][j][r] + bb) * scale);
            }
    }
}

// ---------------------------------------------------------------------------
// Retention v5: 128-wide q-tile, double-buffered K/V DMA prefetch,
// Ps reuses the dead Qs region (XOR-swizzled, unpadded, 16 KB).
// Qb pre-scaled 1/8; VT pre-scaled gamma^{-(m&63)}; per-tile decay in P;
// epilogue scale gamma^{nl}. Total LDS 48 KB.
// ---------------------------------------------------------------------------
__global__ __launch_bounds__(256)
void retention_mfma5(const ushort_t* __restrict__ Qb, const ushort_t* __restrict__ Kb,
                     const ushort_t* __restrict__ VT, const float* __restrict__ gammas,
                     float* __restrict__ Out) {
    __shared__ ushort_t smem[24576];
    // [0,8192): Qs then Ps (128x64)  [8192,16384): Ks x2  [16384,24576): Vt x2
    ushort_t* QsPs = smem;
    const int tid = threadIdx.x;
    const int h = blockIdx.y, b = blockIdx.z;
    const int ntx = (b == 1) ? (15 - blockIdx.x) : blockIdx.x;   // load balance
    const int n0 = ntx * 128;
    const float lg  = log2f(gammas[h]);
    const float g64 = exp2f(64.0f * lg);
    const int w = tid >> 6, lane = tid & 63, quad = lane >> 4, l15 = lane & 15;
    const int l8 = lane & 7, lr8 = lane >> 3;
    const int nl = w * 16 + l15;
    const size_t bS = (size_t)b * S_;
    const size_t vrow0 = (size_t)((b * H_ + h) * HD_);

    auto stageKV = [&](int m0g, int bufo) {
        #pragma unroll
        for (int t = 0; t < 2; ++t) {
            const int row = w * 16 + t * 8 + lr8;
            const int gc = ((l8 ^ (row & 7)) << 3);
            dma16(Kb + (bS + m0g + row) * D_ + h * HD_ + gc,
                  &smem[8192 + bufo + row * 64 + l8 * 8]);
            dma16(VT + (vrow0 + row) * S_ + m0g + gc,
                  &smem[16384 + bufo + row * 64 + l8 * 8]);
        }
    };

    // stage Q + first K/V tile
    #pragma unroll
    for (int t = 0; t < 4; ++t) {
        const int row = w * 32 + t * 8 + lr8;
        const int gc = ((l8 ^ (row & 7)) << 3);
        dma16(Qb + (bS + n0 + row) * D_ + h * HD_ + gc, &QsPs[row * 64 + l8 * 8]);
    }
    stageKV(0, 0);
    __syncthreads();
    bf16x8 qf[2][2];
    #pragma unroll
    for (int hf = 0; hf < 2; ++hf)
        #pragma unroll
        for (int kk = 0; kk < 2; ++kk)
            qf[hf][kk] = fragr(QsPs, hf * 64 + nl, kk * 4 + quad);
    __syncthreads();   // all waves done reading Qs before Ps overwrites it

    f32x4 o[2][4] = {};
    const int tl = 2 * ntx + 1;

    for (int mt = 0; mt <= tl; ++mt) {
        const int bufo = (mt & 1) * 4096;
        if (mt < tl) stageKV((mt + 1) * 64, 4096 - bufo);   // prefetch next tile
        const ushort_t* Ksc = smem + 8192 + bufo;
        const ushort_t* Vtc = smem + 16384 + bufo;
        const bool act0  = (mt <= 2 * ntx);
        const bool diag0 = (mt == 2 * ntx);
        const bool diag1 = (mt == tl);
        const float tsc0 = exp2f((float)(64 * (2 * ntx - mt)) * lg);
        const float tsc1 = tsc0 * g64;

        #pragma unroll
        for (int mt2 = 0; mt2 < 4; ++mt2) {
            bf16x8 kf0 = fragr(Ksc, mt2 * 16 + l15, quad);
            bf16x8 kf1 = fragr(Ksc, mt2 * 16 + l15, 4 + quad);
            const int mbase = mt2 * 16 + quad * 4;
            const int chunk = mbase >> 3;
            if (act0) {
                f32x4 s = {};
                s = __builtin_amdgcn_mfma_f32_16x16x32_bf16(kf0, qf[0][0], s, 0, 0, 0);
                s = __builtin_amdgcn_mfma_f32_16x16x32_bf16(kf1, qf[0][1], s, 0, 0, 0);
                #pragma unroll
                for (int r = 0; r < 4; ++r) {
                    float v2 = s[r] * tsc0;
                    s[r] = (diag0 && nl < mbase + r) ? 0.0f : v2;
                }
                uint2 pw; pw.x = pkt(s[0], s[1]); pw.y = pkt(s[2], s[3]);
                *(uint2*)&QsPs[nl * 64 + ((chunk ^ (nl & 7)) << 3) + (mbase & 7)] = pw;
            }
            {
                f32x4 s = {};
                s = __builtin_amdgcn_mfma_f32_16x16x32_bf16(kf0, qf[1][0], s, 0, 0, 0);
                s = __builtin_amdgcn_mfma_f32_16x16x32_bf16(kf1, qf[1][1], s, 0, 0, 0);
                #pragma unroll
                for (int r = 0; r < 4; ++r) {
                    float v2 = s[r] * tsc1;
                    s[r] = (diag1 && nl < mbase + r) ? 0.0f : v2;
                }
                uint2 pw; pw.x = pkt(s[0], s[1]); pw.y = pkt(s[2], s[3]);
                const int r1 = 64 + nl;
                *(uint2*)&QsPs[r1 * 64 + ((chunk ^ (r1 & 7)) << 3) + (mbase & 7)] = pw;
            }
        }

        // O^T += Vt . P^T   (Ps rows are wave-private; no barrier needed)
        bf16x8 pf00, pf01, pf10, pf11;
        if (act0) {
            pf00 = fragr(QsPs, nl, quad);
            pf01 = fragr(QsPs, nl, 4 + quad);
        }
        pf10 = fragr(QsPs, 64 + nl, quad);
        pf11 = fragr(QsPs, 64 + nl, 4 + quad);
        #pragma unroll
        for (int ct = 0; ct < 4; ++ct) {
            bf16x8 vf0 = fragr(Vtc, ct * 16 + l15, quad);
            bf16x8 vf1 = fragr(Vtc, ct * 16 + l15, 4 + quad);
            if (act0) {
                o[0][ct] = __builtin_amdgcn_mfma_f32_16x16x32_bf16(vf0, pf00, o[0][ct], 0, 0, 0);
                o[0][ct] = __builtin_amdgcn_mfma_f32_16x16x32_bf16(vf1, pf01, o[0][ct], 0, 0, 0);
            }
            o[1][ct] = __builtin_amdgcn_mfma_f32_16x16x32_bf16(vf0, pf10, o[1][ct], 0, 0, 0);
            o[1][ct] = __builtin_amdgcn_mfma_f32_16x16x32_bf16(vf1, pf11, o[1][ct], 0, 0, 0);
        }
        __syncthreads();   // drains prefetch DMA + protects K/V buffer swap
    }

    const float esc = exp2f((float)nl * lg);
    #pragma unroll
    for (int hf = 0; hf < 2; ++hf) {
        const size_t ob = (bS + n0 + hf * 64 + nl) * D_ + h * HD_;
        #pragma unroll
        for (int ct = 0; ct < 4; ++ct) {
            f32x4 t = o[hf][ct] * esc;
            *(f32x4*)(Out + ob + ct * 16 + quad * 4) = t;
        }
    }
}

// ---------------------------------------------------------------------------
extern "C" void kernel_launch(void* const* d_in, const int* in_sizes, int n_in,
                              void* d_out, int out_size, void* d_ws, size_t ws_size,
                              hipStream_t stream) {
    const float* q      = (const float*)d_in[0];
    const float* k      = (const float*)d_in[1];
    const float* v      = (const float*)d_in[2];
    const float* W_in   = (const float*)d_in[3];
    const float* b_in   = (const float*)d_in[4];
    const float* W_gate = (const float*)d_in[5];
    const float* b_gate = (const float*)d_in[6];
    const float* W_out  = (const float*)d_in[7];
    const float* b_out  = (const float*)d_in[8];
    const float* gammas = (const float*)d_in[9];
    float* out = (float*)d_out;

    char* ws = (char*)d_ws;
    const size_t MB = 1024 * 1024;
    float*    Hloc    = (float*)(ws);                 // 16 MB (dead after scan_fix)
    ushort_t* Pp      = (ushort_t*)(ws + 16 * MB);    //  8 MB (dead after scan_fix)
    ushort_t* h_bf    = (ushort_t*)(ws + 24 * MB);    //  8 MB
    ushort_t* q_bf    = (ushort_t*)(ws + 32 * MB);    //  8 MB (reused as qp_bf)
    ushort_t* WT_in   = (ushort_t*)(ws + 40 * MB);    //  2 MB
    ushort_t* WT_gate = (ushort_t*)(ws + 42 * MB);    //  2 MB
    ushort_t* WT_out  = (ushort_t*)(ws + 44 * MB);    //  2 MB
    float*    cA      = (float*)(ws + 46 * MB);       // 512 KB
    float*    cU      = (float*)(ws + 46 * MB + 512 * 1024);
    float*    cIn     = (float*)(ws + 47 * MB);
    ushort_t* k_bf    = (ushort_t*)(ws);              // aliases Hloc (8 MB)
    ushort_t* VT      = (ushort_t*)(ws + 8 * MB);     // aliases Hloc (8 MB)
    ushort_t* qp_bf   = q_bf;

    transp_cvt3<<<dim3(D_ / 32, D_ / 32, 3), 256, 0, stream>>>(
        W_in, W_gate, W_out, WT_in, WT_gate, WT_out);
    cvt_bf16<<<(M_ * D_) / (256 * 4), 256, 0, stream>>>(q, q_bf);

    gemm_dual_scan<<<dim3(D_ / 64, M_ / 128), 256, 0, stream>>>(
        q_bf, WT_in, WT_gate, b_in, b_gate, Hloc, Pp, cA, cU);

    scan_pass2<<<32, 64, 0, stream>>>(cA, cU, cIn);
    scan_fix<<<(M_ * D_) / 1024, 256, 0, stream>>>(Hloc, Pp, cIn, h_bf);

    // Hloc/Pp dead -> k_bf + VT reuse the front of the workspace
    kv_cvt<<<dim3(S_ / 64, H_, B_), 256, 0, stream>>>(k, v, gammas, k_bf, VT);

    gemm_out_a<<<dim3(D_ / 64, M_ / 128), 256, 0, stream>>>(
        h_bf, WT_out, b_out, 0.125f, qp_bf);

    retention_mfma5<<<dim3(S_ / 128, H_, B_), 256, 0, stream>>>(
        qp_bf, k_bf, VT, gammas, out);
}

// Round 8
// 188.608 us; speedup vs baseline: 5.0982x; 1.1562x over previous
//
#include <hip/hip_runtime.h>
#include <math.h>

#define B_  2
#define S_  2048
#define D_  1024
#define H_  16
#define HD_ 64
#define M_  (B_*S_)

typedef unsigned short ushort_t;
typedef unsigned int   uint_t;
typedef __attribute__((ext_vector_type(8))) short bf16x8;
typedef __attribute__((ext_vector_type(4))) float f32x4;

__device__ __forceinline__ ushort_t f2bf(float f) {
    uint_t u = __builtin_bit_cast(uint_t, f);
    u += 0x7FFFu + ((u >> 16) & 1u);           // RNE
    return (ushort_t)(u >> 16);
}
__device__ __forceinline__ float bf2f(ushort_t h) {
    uint_t u = (uint_t)h << 16;
    return __builtin_bit_cast(float, u);
}
// truncating pack: two f32 -> (bf16(lo) | bf16(hi)<<16), one v_perm_b32
__device__ __forceinline__ uint_t pkt(float lo, float hi) {
    return __builtin_amdgcn_perm(__builtin_bit_cast(uint_t, hi),
                                 __builtin_bit_cast(uint_t, lo), 0x07060302u);
}
// async global->LDS, 16B per lane; lds addr = wave-uniform base + lane*16
__device__ __forceinline__ void dma16(const ushort_t* g, ushort_t* l) {
    __builtin_amdgcn_global_load_lds(
        (const __attribute__((address_space(1))) uint_t*)g,
        (__attribute__((address_space(3))) uint_t*)l, 16, 0, 0);
}
// swizzled fragment read from unpadded [row][64] bf16 tile
__device__ __forceinline__ bf16x8 fragr(const ushort_t* base, int row, int chunk) {
    return *(const bf16x8*)&base[row * 64 + (((chunk ^ (row & 7)) << 3))];
}

// ---------------------------------------------------------------------------
// Transpose + convert all three weights: W [K][N] f32 -> WT [N][K] bf16
// ---------------------------------------------------------------------------
__global__ __launch_bounds__(256)
void transp_cvt3(const float* __restrict__ W0, const float* __restrict__ W1,
                 const float* __restrict__ W2, ushort_t* __restrict__ T0,
                 ushort_t* __restrict__ T1, ushort_t* __restrict__ T2) {
    __shared__ float T[32][36];
    const float*  W  = (blockIdx.z == 0) ? W0 : (blockIdx.z == 1) ? W1 : W2;
    ushort_t*     WT = (blockIdx.z == 0) ? T0 : (blockIdx.z == 1) ? T1 : T2;
    const int kt = blockIdx.x, nt = blockIdx.y;
    const int t = threadIdx.x;
    const int rr = t >> 3, cc = (t & 7) * 4;
    float4 w4 = *(const float4*)(W + (size_t)(kt * 32 + rr) * D_ + nt * 32 + cc);
    T[rr][cc + 0] = w4.x; T[rr][cc + 1] = w4.y; T[rr][cc + 2] = w4.z; T[rr][cc + 3] = w4.w;
    __syncthreads();
    ushort_t o[4];
    #pragma unroll
    for (int j = 0; j < 4; ++j) o[j] = f2bf(T[cc + j][rr]);
    *(ushort4*)(WT + (size_t)(nt * 32 + rr) * D_ + kt * 32 + cc) =
        make_ushort4(o[0], o[1], o[2], o[3]);
}

__global__ __launch_bounds__(256)
void cvt_bf16(const float* __restrict__ X, ushort_t* __restrict__ Y) {
    const int i = (blockIdx.x * 256 + threadIdx.x) * 4;
    float4 x = *(const float4*)(X + i);
    *(ushort4*)(Y + i) = make_ushort4(f2bf(x.x), f2bf(x.y), f2bf(x.z), f2bf(x.w));
}

// ---------------------------------------------------------------------------
// K -> Kb bf16 (straight); V -> VT [B,H,HD,S] bf16 * gamma^{-ml};
// plus per-chunk outer product G^T[val][kappa] = sum_ml V'[ml][val]*K[ml][kappa]
// (f32) for the chunkwise-recurrent state.
// ---------------------------------------------------------------------------
__global__ __launch_bounds__(256)
void kv_cvt_g(const float* __restrict__ K, const float* __restrict__ V,
              const float* __restrict__ gammas, ushort_t* __restrict__ Kb,
              ushort_t* __restrict__ VT, float* __restrict__ Gg) {
    __shared__ ushort_t Tv[64 * 72];   // [val][ml]
    __shared__ ushort_t Tk[64 * 72];   // [kappa][ml]
    const int mt = blockIdx.x, h = blockIdx.y, b = blockIdx.z;
    const int m0 = mt * 64;
    const int tid = threadIdx.x;
    const int r = tid >> 2, c0 = (tid & 3) * 16;
    const float lg = log2f(gammas[h]);
    const float gm = exp2f(-(float)r * lg);   // gamma^{-ml}, ml = r
    // K: straight convert -> Kb, and scatter K^T into Tk
    {
        const float* src = K + ((size_t)(b * S_ + m0 + r)) * D_ + h * HD_ + c0;
        ushort_t kb[16];
        #pragma unroll
        for (int j4 = 0; j4 < 4; ++j4) {
            float4 x = *(const float4*)(src + j4 * 4);
            kb[j4 * 4 + 0] = f2bf(x.x); kb[j4 * 4 + 1] = f2bf(x.y);
            kb[j4 * 4 + 2] = f2bf(x.z); kb[j4 * 4 + 3] = f2bf(x.w);
        }
        ushort_t* dst = Kb + ((size_t)(b * S_ + m0 + r)) * D_ + h * HD_ + c0;
        *(uint4*)(dst + 0) = *(const uint4*)&kb[0];
        *(uint4*)(dst + 8) = *(const uint4*)&kb[8];
        #pragma unroll
        for (int j = 0; j < 16; ++j) Tk[(c0 + j) * 72 + r] = kb[j];
    }
    // V: scale + transpose into Tv
    {
        const float* src = V + ((size_t)(b * S_ + m0 + r)) * D_ + h * HD_ + c0;
        #pragma unroll
        for (int j4 = 0; j4 < 4; ++j4) {
            float4 x = *(const float4*)(src + j4 * 4);
            Tv[(c0 + j4 * 4 + 0) * 72 + r] = f2bf(x.x * gm);
            Tv[(c0 + j4 * 4 + 1) * 72 + r] = f2bf(x.y * gm);
            Tv[(c0 + j4 * 4 + 2) * 72 + r] = f2bf(x.z * gm);
            Tv[(c0 + j4 * 4 + 3) * 72 + r] = f2bf(x.w * gm);
        }
    }
    __syncthreads();
    // VT global write
    {
        ushort_t* dst = VT + ((size_t)((b * H_ + h) * HD_ + r)) * S_ + m0 + c0;
        *(uint4*)(dst + 0) = *(const uint4*)&Tv[r * 72 + c0 + 0];
        *(uint4*)(dst + 8) = *(const uint4*)&Tv[r * 72 + c0 + 8];
    }
    // G^T = Tv . Tk^T via MFMA: A = Tv rows (val), B = Tk rows (kappa)
    const int w = tid >> 6, lane = tid & 63, quad = lane >> 4, l15 = lane & 15;
    bf16x8 af0 = *(const bf16x8*)&Tv[(w * 16 + l15) * 72 + quad * 8];
    bf16x8 af1 = *(const bf16x8*)&Tv[(w * 16 + l15) * 72 + 32 + quad * 8];
    float* gout = Gg + ((size_t)((b * H_ + h) * 32 + mt)) * 4096;
    #pragma unroll
    for (int kt2 = 0; kt2 < 4; ++kt2) {
        bf16x8 bf0 = *(const bf16x8*)&Tk[(kt2 * 16 + l15) * 72 + quad * 8];
        bf16x8 bf1 = *(const bf16x8*)&Tk[(kt2 * 16 + l15) * 72 + 32 + quad * 8];
        f32x4 g = {};
        g = __builtin_amdgcn_mfma_f32_16x16x32_bf16(af0, bf0, g, 0, 0, 0);
        g = __builtin_amdgcn_mfma_f32_16x16x32_bf16(af1, bf1, g, 0, 0, 0);
        #pragma unroll
        for (int reg = 0; reg < 4; ++reg)
            gout[(w * 16 + quad * 4 + reg) * 64 + kt2 * 16 + l15] = g[reg];
    }
}

// ---------------------------------------------------------------------------
// State scan: S_c = gamma^64 * (S_{c-1} + G_{c-1}), S_0 = 0; store S_c bf16.
// Grid (4 val-slabs, H, B); thread owns a float4 run of kappa.
// ---------------------------------------------------------------------------
__global__ __launch_bounds__(256)
void state_scan(const float* __restrict__ Gg, const float* __restrict__ gammas,
                ushort_t* __restrict__ Sb) {
    const int sl = blockIdx.x, h = blockIdx.y, b = blockIdx.z;
    const float g64 = exp2f(64.0f * log2f(gammas[h]));
    const int r = threadIdx.x >> 4;              // row in slab 0..15
    const int cb = (threadIdx.x & 15) * 4;       // kappa base
    const size_t base = ((size_t)((b * H_ + h) * 32)) * 4096 + (sl * 16 + r) * 64 + cb;
    float4 S = make_float4(0.f, 0.f, 0.f, 0.f);
    for (int c = 0; c < 32; ++c) {
        ushort4 sb;
        sb.x = f2bf(S.x); sb.y = f2bf(S.y); sb.z = f2bf(S.z); sb.w = f2bf(S.w);
        *(ushort4*)(Sb + base + (size_t)c * 4096) = sb;
        float4 G = *(const float4*)(Gg + base + (size_t)c * 4096);
        S.x = g64 * (S.x + G.x); S.y = g64 * (S.y + G.y);
        S.z = g64 * (S.z + G.z); S.w = g64 * (S.w + G.w);
    }
}

// ---------------------------------------------------------------------------
// Fused dual GEMM + chunk-scan epilogue, double-buffered DMA staging.
// ---------------------------------------------------------------------------
__global__ __launch_bounds__(256)
void gemm_dual_scan(const ushort_t* __restrict__ A, const ushort_t* __restrict__ BTi,
                    const ushort_t* __restrict__ BTg, const float* __restrict__ bi,
                    const float* __restrict__ bg, float* __restrict__ Hloc,
                    ushort_t* __restrict__ Pp, float* __restrict__ cA,
                    float* __restrict__ cU) {
    __shared__ ushort_t smem[32768];   // 64 KB = 2 x (As 8192 | Bi 4096 | Bg 4096)
    const int tid = threadIdx.x;
    const int n0 = blockIdx.x * 64, m0 = blockIdx.y * 128;
    const int w = tid >> 6, lane = tid & 63, quad = lane >> 4, l15 = lane & 15;
    const int wr = (w >> 1) * 64, wc = (w & 1) * 32;
    const int l8 = lane & 7, lr8 = lane >> 3;

    f32x4 acc_i[4][2] = {};
    f32x4 acc_g[4][2] = {};

    auto stage = [&](int k0, int bufo) {
        #pragma unroll
        for (int t = 0; t < 4; ++t) {
            const int row = w * 32 + t * 8 + lr8;
            const int gc = ((l8 ^ (row & 7)) << 3);
            dma16(A + (size_t)(m0 + row) * D_ + k0 + gc, &smem[bufo + row * 64 + l8 * 8]);
        }
        #pragma unroll
        for (int t = 0; t < 2; ++t) {
            const int row = w * 16 + t * 8 + lr8;
            const int gc = ((l8 ^ (row & 7)) << 3);
            dma16(BTi + (size_t)(n0 + row) * D_ + k0 + gc, &smem[bufo + 8192 + row * 64 + l8 * 8]);
            dma16(BTg + (size_t)(n0 + row) * D_ + k0 + gc, &smem[bufo + 12288 + row * 64 + l8 * 8]);
        }
    };

    stage(0, 0);
    __syncthreads();
    for (int t = 0; t < 16; ++t) {
        const int bufo = (t & 1) * 16384;
        if (t < 15) stage((t + 1) * 64, 16384 - bufo);
        const ushort_t* As = smem + bufo;
        const ushort_t* Bi = smem + bufo + 8192;
        const ushort_t* Bg = smem + bufo + 12288;
        #pragma unroll
        for (int kk = 0; kk < 2; ++kk) {
            bf16x8 af[4], bfi[2], bfg[2];
            #pragma unroll
            for (int i = 0; i < 4; ++i)
                af[i] = fragr(As, wr + 16 * i + l15, kk * 4 + quad);
            #pragma unroll
            for (int j = 0; j < 2; ++j) {
                bfi[j] = fragr(Bi, wc + 16 * j + l15, kk * 4 + quad);
                bfg[j] = fragr(Bg, wc + 16 * j + l15, kk * 4 + quad);
            }
            #pragma unroll
            for (int i = 0; i < 4; ++i)
                #pragma unroll
                for (int j = 0; j < 2; ++j) {
                    acc_i[i][j] = __builtin_amdgcn_mfma_f32_16x16x32_bf16(
                        af[i], bfi[j], acc_i[i][j], 0, 0, 0);
                    acc_g[i][j] = __builtin_amdgcn_mfma_f32_16x16x32_bf16(
                        af[i], bfg[j], acc_g[i][j], 0, 0, 0);
                }
        }
        __syncthreads();
    }

    ushort_t* Us = smem;
    ushort_t* Gu = smem + 8448;
    #pragma unroll
    for (int j = 0; j < 2; ++j) {
        const int n = wc + 16 * j + l15;
        const float bbi = bi[n0 + n], bbg = bg[n0 + n];
        #pragma unroll
        for (int i = 0; i < 4; ++i) {
            #pragma unroll
            for (int r = 0; r < 4; ++r) {
                const int m = wr + 16 * i + quad * 4 + r;
                Us[m * 66 + n] = f2bf(acc_i[i][j][r] + bbi);
                float g = 1.0f / (1.0f + __expf(-(acc_g[i][j][r] + bbg)));
                Gu[m * 66 + n] = (ushort_t)__float2uint_rn(g * 65535.0f);
            }
        }
    }
    __syncthreads();

    const int nl = tid & 63, c = tid >> 6;
    const int gmb = m0 + c * 32;
    const size_t gbase = (size_t)gmb * D_ + n0 + nl;
    float Aa = 1.0f, hh = 0.0f;
    #pragma unroll 4
    for (int j = 0; j < 32; ++j) {
        const float g = (float)Gu[(c * 32 + j) * 66 + nl] * (1.0f / 65535.0f);
        const float u = bf2f(Us[(c * 32 + j) * 66 + nl]);
        Aa *= g;
        hh = fmaf(g, hh, u);
        Pp[gbase + (size_t)j * D_] = f2bf(Aa);
        Hloc[gbase + (size_t)j * D_] = hh;
    }
    const int bb = gmb >> 11;
    const int ch = (gmb & 2047) >> 5;
    const int ci = ((bb * 64 + ch) << 10) + n0 + nl;
    cA[ci] = Aa;
    cU[ci] = hh;
}

__global__ __launch_bounds__(64)
void scan_pass2(const float* __restrict__ cA, const float* __restrict__ cU,
                float* __restrict__ cIn) {
    const int t = blockIdx.x * 64 + threadIdx.x;
    const int d = t & 1023, b = t >> 10;
    float h = 0.0f;
    for (int c0 = 0; c0 < 64; c0 += 16) {
        float Av[16], Uv[16];
        #pragma unroll
        for (int j = 0; j < 16; ++j) {
            const int idx = ((b * 64 + c0 + j) << 10) + d;
            Av[j] = cA[idx]; Uv[j] = cU[idx];
        }
        #pragma unroll
        for (int j = 0; j < 16; ++j) {
            cIn[((b * 64 + c0 + j) << 10) + d] = h;
            h = fmaf(Av[j], h, Uv[j]);
        }
    }
}

__global__ __launch_bounds__(256)
void scan_fix(const float* __restrict__ Hloc, const ushort_t* __restrict__ Pp,
              const float* __restrict__ cIn, ushort_t* __restrict__ hout) {
    const int i = (blockIdx.x * 256 + threadIdx.x) * 4;
    const int m = i >> 10, d = i & 1023;
    const int b = m >> 11, ch = (m & 2047) >> 5;
    float4 hl = *(const float4*)(Hloc + i);
    ushort4 p4 = *(const ushort4*)(Pp + i);
    float4 ci = *(const float4*)(cIn + ((b * 64 + ch) << 10) + d);
    ushort4 o;
    o.x = f2bf(fmaf(ci.x, bf2f(p4.x), hl.x));
    o.y = f2bf(fmaf(ci.y, bf2f(p4.y), hl.y));
    o.z = f2bf(fmaf(ci.z, bf2f(p4.z), hl.z));
    o.w = f2bf(fmaf(ci.w, bf2f(p4.w), hl.w));
    *(ushort4*)(hout + i) = o;
}

// ---------------------------------------------------------------------------
// Single GEMM (W_out), double-buffered DMA: C = (A.WT + bias)*scale -> bf16
// ---------------------------------------------------------------------------
__global__ __launch_bounds__(256)
void gemm_out_a(const ushort_t* __restrict__ A, const ushort_t* __restrict__ BT,
                const float* __restrict__ bias, float scale,
                ushort_t* __restrict__ Cb) {
    __shared__ ushort_t smem[24576];   // 48 KB = 2 x (As 8192 | Bs 4096)
    const int tid = threadIdx.x;
    const int n0 = blockIdx.x * 64, m0 = blockIdx.y * 128;
    const int w = tid >> 6, lane = tid & 63, quad = lane >> 4, l15 = lane & 15;
    const int wr = (w >> 1) * 64, wc = (w & 1) * 32;
    const int l8 = lane & 7, lr8 = lane >> 3;

    f32x4 acc[4][2] = {};

    auto stage = [&](int k0, int bufo) {
        #pragma unroll
        for (int t = 0; t < 4; ++t) {
            const int row = w * 32 + t * 8 + lr8;
            const int gc = ((l8 ^ (row & 7)) << 3);
            dma16(A + (size_t)(m0 + row) * D_ + k0 + gc, &smem[bufo + row * 64 + l8 * 8]);
        }
        #pragma unroll
        for (int t = 0; t < 2; ++t) {
            const int row = w * 16 + t * 8 + lr8;
            const int gc = ((l8 ^ (row & 7)) << 3);
            dma16(BT + (size_t)(n0 + row) * D_ + k0 + gc, &smem[bufo + 8192 + row * 64 + l8 * 8]);
        }
    };

    stage(0, 0);
    __syncthreads();
    for (int t = 0; t < 16; ++t) {
        const int bufo = (t & 1) * 12288;
        if (t < 15) stage((t + 1) * 64, 12288 - bufo);
        const ushort_t* As = smem + bufo;
        const ushort_t* Bs = smem + bufo + 8192;
        #pragma unroll
        for (int kk = 0; kk < 2; ++kk) {
            bf16x8 af[4], bf[2];
            #pragma unroll
            for (int i = 0; i < 4; ++i)
                af[i] = fragr(As, wr + 16 * i + l15, kk * 4 + quad);
            #pragma unroll
            for (int j = 0; j < 2; ++j)
                bf[j] = fragr(Bs, wc + 16 * j + l15, kk * 4 + quad);
            #pragma unroll
            for (int i = 0; i < 4; ++i)
                #pragma unroll
                for (int j = 0; j < 2; ++j)
                    acc[i][j] = __builtin_amdgcn_mfma_f32_16x16x32_bf16(
                        af[i], bf[j], acc[i][j], 0, 0, 0);
        }
        __syncthreads();
    }

    #pragma unroll
    for (int j = 0; j < 2; ++j) {
        const int n = n0 + wc + 16 * j + l15;
        const float bb = bias[n];
        #pragma unroll
        for (int i = 0; i < 4; ++i)
            #pragma unroll
            for (int r = 0; r < 4; ++r) {
                const int m = m0 + wr + 16 * i + quad * 4 + r;
                Cb[(size_t)m * D_ + n] = f2bf((acc[i][j][r] + bb) * scale);
            }
    }
}

// ---------------------------------------------------------------------------
// Retention, chunkwise-recurrent: one 64-row q-tile per block, uniform work.
// out^T[val][nl] = S^T.q + VT.(masked QK^T)  ; epilogue scale gamma^{nl}.
// Qb pre-scaled 1/8; VT pre-scaled gamma^{-ml}; Sb = state entering chunk.
// LDS 40 KB -> 4 blocks/CU.
// ---------------------------------------------------------------------------
__global__ __launch_bounds__(256)
void retention_chunk(const ushort_t* __restrict__ Qb, const ushort_t* __restrict__ Kb,
                     const ushort_t* __restrict__ VT, const ushort_t* __restrict__ Sb,
                     const float* __restrict__ gammas, float* __restrict__ Out) {
    __shared__ ushort_t smem[20480];   // 40 KB
    ushort_t* Qs = smem;               // [nl][64]
    ushort_t* Ks = smem + 4096;        // [ml][64]
    ushort_t* Vt = smem + 8192;        // [val][ml]
    ushort_t* Ss = smem + 12288;       // [val][kappa]
    ushort_t* Ps = smem + 16384;       // [nl][ml] swizzled
    const int tid = threadIdx.x;
    const int nt = blockIdx.x, h = blockIdx.y, b = blockIdx.z;
    const int n0 = nt * 64;
    const float lg = log2f(gammas[h]);
    const int w = tid >> 6, lane = tid & 63, quad = lane >> 4, l15 = lane & 15;
    const int l8 = lane & 7, lr8 = lane >> 3;
    const int nl = w * 16 + l15;
    const size_t bS = (size_t)b * S_;
    const size_t vrow0 = (size_t)((b * H_ + h) * HD_);
    const size_t sbase = ((size_t)((b * H_ + h) * 32 + nt)) * 4096;

    #pragma unroll
    for (int t = 0; t < 2; ++t) {
        const int row = w * 16 + t * 8 + lr8;
        const int gc = ((l8 ^ (row & 7)) << 3);
        dma16(Qb + (bS + n0 + row) * D_ + h * HD_ + gc, &Qs[row * 64 + l8 * 8]);
        dma16(Kb + (bS + n0 + row) * D_ + h * HD_ + gc, &Ks[row * 64 + l8 * 8]);
        dma16(VT + (vrow0 + row) * S_ + n0 + gc, &Vt[row * 64 + l8 * 8]);
        dma16(Sb + sbase + (size_t)row * 64 + gc, &Ss[row * 64 + l8 * 8]);
    }
    __syncthreads();

    bf16x8 qf0 = fragr(Qs, nl, quad);
    bf16x8 qf1 = fragr(Qs, nl, 4 + quad);

    f32x4 o[4] = {};
    // cross-chunk: o[ct] += S^T-rows(A) x Q-rows(B)
    #pragma unroll
    for (int ct = 0; ct < 4; ++ct) {
        bf16x8 sf0 = fragr(Ss, ct * 16 + l15, quad);
        bf16x8 sf1 = fragr(Ss, ct * 16 + l15, 4 + quad);
        o[ct] = __builtin_amdgcn_mfma_f32_16x16x32_bf16(sf0, qf0, o[ct], 0, 0, 0);
        o[ct] = __builtin_amdgcn_mfma_f32_16x16x32_bf16(sf1, qf1, o[ct], 0, 0, 0);
    }
    // intra-chunk scores^T[ml][nl], causal mask, pack -> Ps
    #pragma unroll
    for (int mt2 = 0; mt2 < 4; ++mt2) {
        bf16x8 kf0 = fragr(Ks, mt2 * 16 + l15, quad);
        bf16x8 kf1 = fragr(Ks, mt2 * 16 + l15, 4 + quad);
        f32x4 s = {};
        s = __builtin_amdgcn_mfma_f32_16x16x32_bf16(kf0, qf0, s, 0, 0, 0);
        s = __builtin_amdgcn_mfma_f32_16x16x32_bf16(kf1, qf1, s, 0, 0, 0);
        const int mbase = mt2 * 16 + quad * 4;
        #pragma unroll
        for (int r = 0; r < 4; ++r)
            if (nl < mbase + r) s[r] = 0.0f;
        uint2 pw; pw.x = pkt(s[0], s[1]); pw.y = pkt(s[2], s[3]);
        const int chunk = mbase >> 3;
        *(uint2*)&Ps[nl * 64 + ((chunk ^ (nl & 7)) << 3) + (mbase & 7)] = pw;
    }
    // PV: o[ct] += Vt-rows(A) x Ps-row-nl(B)   (Ps rows wave-private)
    bf16x8 pf0 = fragr(Ps, nl, quad);
    bf16x8 pf1 = fragr(Ps, nl, 4 + quad);
    #pragma unroll
    for (int ct = 0; ct < 4; ++ct) {
        bf16x8 vf0 = fragr(Vt, ct * 16 + l15, quad);
        bf16x8 vf1 = fragr(Vt, ct * 16 + l15, 4 + quad);
        o[ct] = __builtin_amdgcn_mfma_f32_16x16x32_bf16(vf0, pf0, o[ct], 0, 0, 0);
        o[ct] = __builtin_amdgcn_mfma_f32_16x16x32_bf16(vf1, pf1, o[ct], 0, 0, 0);
    }

    const float esc = exp2f((float)nl * lg);
    const size_t ob = (bS + n0 + nl) * D_ + h * HD_;
    #pragma unroll
    for (int ct = 0; ct < 4; ++ct) {
        f32x4 t = o[ct] * esc;
        *(f32x4*)(Out + ob + ct * 16 + quad * 4) = t;
    }
}

// ---------------------------------------------------------------------------
extern "C" void kernel_launch(void* const* d_in, const int* in_sizes, int n_in,
                              void* d_out, int out_size, void* d_ws, size_t ws_size,
                              hipStream_t stream) {
    const float* q      = (const float*)d_in[0];
    const float* k      = (const float*)d_in[1];
    const float* v      = (const float*)d_in[2];
    const float* W_in   = (const float*)d_in[3];
    const float* b_in   = (const float*)d_in[4];
    const float* W_gate = (const float*)d_in[5];
    const float* b_gate = (const float*)d_in[6];
    const float* W_out  = (const float*)d_in[7];
    const float* b_out  = (const float*)d_in[8];
    const float* gammas = (const float*)d_in[9];
    float* out = (float*)d_out;

    char* ws = (char*)d_ws;
    const size_t MB = 1024 * 1024;
    float*    Hloc    = (float*)(ws);                 // [0,16) dead after scan_fix
    ushort_t* Pp      = (ushort_t*)(ws + 16 * MB);    // [16,24) dead after scan_fix
    ushort_t* h_bf    = (ushort_t*)(ws + 24 * MB);    // [24,32) dead after gemm_out
    ushort_t* q_bf    = (ushort_t*)(ws + 32 * MB);    // [32,40) live (reused as qp)
    ushort_t* WT_in   = (ushort_t*)(ws + 40 * MB);
    ushort_t* WT_gate = (ushort_t*)(ws + 42 * MB);
    ushort_t* WT_out  = (ushort_t*)(ws + 44 * MB);
    float*    cA      = (float*)(ws + 46 * MB);
    float*    cU      = (float*)(ws + 46 * MB + 512 * 1024);
    float*    cIn     = (float*)(ws + 47 * MB);
    ushort_t* k_bf    = (ushort_t*)(ws);              // [0,8)  after scan_fix
    ushort_t* VT      = (ushort_t*)(ws + 8 * MB);     // [8,16) after scan_fix
    float*    Gg      = (float*)(ws + 16 * MB);       // [16,32) after gemm_out
    ushort_t* Sb      = (ushort_t*)(ws + 40 * MB);    // [40,48) after gemm_out
    ushort_t* qp_bf   = q_bf;

    transp_cvt3<<<dim3(D_ / 32, D_ / 32, 3), 256, 0, stream>>>(
        W_in, W_gate, W_out, WT_in, WT_gate, WT_out);
    cvt_bf16<<<(M_ * D_) / (256 * 4), 256, 0, stream>>>(q, q_bf);

    gemm_dual_scan<<<dim3(D_ / 64, M_ / 128), 256, 0, stream>>>(
        q_bf, WT_in, WT_gate, b_in, b_gate, Hloc, Pp, cA, cU);

    scan_pass2<<<32, 64, 0, stream>>>(cA, cU, cIn);
    scan_fix<<<(M_ * D_) / 1024, 256, 0, stream>>>(Hloc, Pp, cIn, h_bf);

    gemm_out_a<<<dim3(D_ / 64, M_ / 128), 256, 0, stream>>>(
        h_bf, WT_out, b_out, 0.125f, qp_bf);

    kv_cvt_g<<<dim3(S_ / 64, H_, B_), 256, 0, stream>>>(k, v, gammas, k_bf, VT, Gg);
    state_scan<<<dim3(4, H_, B_), 256, 0, stream>>>(Gg, gammas, Sb);

    retention_chunk<<<dim3(S_ / 64, H_, B_), 256, 0, stream>>>(
        qp_bf, k_bf, VT, Sb, gammas, out);
}